// Round 1
// baseline (909.997 us; speedup 1.0000x reference)
//
#include <hip/hip_runtime.h>
#include <hip/hip_bf16.h>
#include <cstdint>

#define B_TOK 8192
#define DIN   1024
#define HID   4096
#define CLS   1000
#define CPAD  1024
#define NE    8
#define NPAIR (B_TOK * 2)
#define PAIR_CAP (NPAIR + NE * 128)  // 17408, multiple of 128
#define PART_BLOCKS 2048

typedef __attribute__((ext_vector_type(8))) short short8;
typedef __attribute__((ext_vector_type(4))) float floatx4;

__device__ __forceinline__ unsigned short f2bf(float f) {
  unsigned int u = __builtin_bit_cast(unsigned int, f);
  u += 0x7fffu + ((u >> 16) & 1u);   // RNE
  return (unsigned short)(u >> 16);
}

// global -> LDS async copy, 16B per lane. LDS dest must be wave-uniform.
__device__ __forceinline__ void gload16(const void* g, void* l) {
  __builtin_amdgcn_global_load_lds(
      (const __attribute__((address_space(1))) void*)(uintptr_t)g,
      (__attribute__((address_space(3))) void*)(unsigned int)(uintptr_t)l,
      16, 0, 0);
}

// ---------------- gating: one wave per token ----------------
__global__ void k_gate(const float* __restrict__ x, const float* __restrict__ Wg,
                       const float* __restrict__ bg, int* __restrict__ counts,
                       float* __restrict__ part, int* __restrict__ topk_e,
                       float* __restrict__ topk_w) {
  int tok = (blockIdx.x * blockDim.x + threadIdx.x) >> 6;
  int lane = threadIdx.x & 63;
  __shared__ float psum[NE];
  if (threadIdx.x < NE) psum[threadIdx.x] = 0.f;
  __syncthreads();

  float acc[NE];
#pragma unroll
  for (int e = 0; e < NE; e++) acc[e] = 0.f;
  const float* xr = x + (size_t)tok * DIN;
  for (int d = lane; d < DIN; d += 64) {
    float xv = xr[d];
    const float* wr = Wg + d * NE;
#pragma unroll
    for (int e = 0; e < NE; e++) acc[e] += xv * wr[e];
  }
#pragma unroll
  for (int e = 0; e < NE; e++)
    for (int off = 32; off; off >>= 1) acc[e] += __shfl_xor(acc[e], off);

  if (lane == 0) {
    float p[NE];
    float m = -1e30f;
#pragma unroll
    for (int e = 0; e < NE; e++) { p[e] = acc[e] + bg[e]; m = fmaxf(m, p[e]); }
    float s = 0.f;
#pragma unroll
    for (int e = 0; e < NE; e++) { p[e] = expf(p[e] - m); s += p[e]; }
    float inv = 1.f / s;
#pragma unroll
    for (int e = 0; e < NE; e++) p[e] *= inv;
    int e0 = 0;
#pragma unroll
    for (int e = 1; e < NE; e++) if (p[e] > p[e0]) e0 = e;
    int e1 = -1;
#pragma unroll
    for (int e = 0; e < NE; e++) {
      if (e == e0) continue;
      if (e1 < 0 || p[e] > p[e1]) e1 = e;
    }
    float wi = 1.f / (p[e0] + p[e1]);
    topk_e[tok * 2] = e0;  topk_e[tok * 2 + 1] = e1;
    topk_w[tok * 2] = p[e0] * wi;  topk_w[tok * 2 + 1] = p[e1] * wi;
    atomicAdd(&counts[e0], 1);
    atomicAdd(&counts[e1], 1);
#pragma unroll
    for (int e = 0; e < NE; e++) atomicAdd(&psum[e], p[e]);
  }
  __syncthreads();
  if (threadIdx.x < NE) part[blockIdx.x * NE + threadIdx.x] = psum[threadIdx.x];
}

// ---------------- setup: offsets, cursors, lb_loss, dummy fill ----------------
__global__ void k_setup(const int* __restrict__ counts, int* __restrict__ offsets_pad,
                        int* __restrict__ cursor, const float* __restrict__ part,
                        int* __restrict__ pair_token, float* __restrict__ out_lb) {
  __shared__ int soff[NE + 1];
  __shared__ float ssum[NE];
  int t = threadIdx.x;
  float loc[NE];
#pragma unroll
  for (int e = 0; e < NE; e++) loc[e] = 0.f;
  for (int i = t; i < PART_BLOCKS; i += blockDim.x)
#pragma unroll
    for (int e = 0; e < NE; e++) loc[e] += part[i * NE + e];
  if (t < NE) ssum[t] = 0.f;
  __syncthreads();
#pragma unroll
  for (int e = 0; e < NE; e++) atomicAdd(&ssum[e], loc[e]);
  __syncthreads();
  if (t == 0) {
    float lb = 0.f;
    for (int e = 0; e < NE; e++) {
      float mean = ssum[e] / (float)B_TOK;
      lb += mean * mean;
    }
    *out_lb = lb * (float)NE;
    int off = 0;
    for (int e = 0; e < NE; e++) {
      soff[e] = off;
      off += ((counts[e] + 127) >> 7) << 7;
    }
    soff[NE] = off;
  }
  __syncthreads();
  if (t <= NE) offsets_pad[t] = soff[t];
  if (t < NE) cursor[t] = soff[t];
  // dummy pairs so every 128-row block is single-expert
  for (int e = 0; e < NE; e++) {
    int s0 = soff[e] + counts[e], s1 = soff[e + 1];
    for (int i = s0 + t; i < s1; i += blockDim.x) pair_token[i] = 0;
  }
}

// ---------------- scatter tokens into expert buckets ----------------
__global__ void k_scatter(const int* __restrict__ topk_e, int* __restrict__ cursor,
                          int* __restrict__ pair_token, int* __restrict__ pos_of) {
  int b = blockIdx.x * blockDim.x + threadIdx.x;
  if (b >= B_TOK) return;
#pragma unroll
  for (int k = 0; k < 2; k++) {
    int e = topk_e[b * 2 + k];
    int pos = atomicAdd(&cursor[e], 1);
    pair_token[pos] = b;
    pos_of[b * 2 + k] = pos;
  }
}

// ---------------- cast x to bf16 ----------------
__global__ void k_cast_x(const float4* __restrict__ x4, ushort4* __restrict__ xb4) {
  int i = blockIdx.x * blockDim.x + threadIdx.x;
  float4 v = x4[i];
  ushort4 o;
  o.x = f2bf(v.x); o.y = f2bf(v.y); o.z = f2bf(v.z); o.w = f2bf(v.w);
  xb4[i] = o;
}

// ---------------- transpose+cast W1: [E][DIN][HID] f32 -> [E][HID][DIN] bf16 ----------------
__global__ void k_trans_w1(const float* __restrict__ W1, unsigned short* __restrict__ W1t) {
  __shared__ float tile[32][33];
  int e = blockIdx.z;
  int n0 = blockIdx.x * 32;  // HID
  int k0 = blockIdx.y * 32;  // DIN
  const float* src = W1 + ((size_t)e * DIN + k0) * HID + n0;
#pragma unroll
  for (int i = 0; i < 4; i++)
    tile[threadIdx.y + i * 8][threadIdx.x] = src[(size_t)(threadIdx.y + i * 8) * HID + threadIdx.x];
  __syncthreads();
  unsigned short* dst = W1t + ((size_t)e * HID + n0) * DIN + k0;
#pragma unroll
  for (int i = 0; i < 4; i++)
    dst[(size_t)(threadIdx.y + i * 8) * DIN + threadIdx.x] = f2bf(tile[threadIdx.x][threadIdx.y + i * 8]);
}

// ---------------- transpose+cast W2: [E][HID][CLS] f32 -> [E][CPAD][HID] bf16 (zero pad) ----------------
__global__ void k_trans_w2(const float* __restrict__ W2, unsigned short* __restrict__ W2t) {
  __shared__ float tile[32][33];
  int e = blockIdx.z;
  int n0 = blockIdx.x * 32;  // CPAD
  int k0 = blockIdx.y * 32;  // HID
#pragma unroll
  for (int i = 0; i < 4; i++) {
    int n = n0 + threadIdx.x;
    float v = 0.f;
    if (n < CLS) v = W2[((size_t)e * HID + k0 + threadIdx.y + i * 8) * CLS + n];
    tile[threadIdx.y + i * 8][threadIdx.x] = v;
  }
  __syncthreads();
  unsigned short* dst = W2t + ((size_t)e * CPAD + n0) * HID + k0;
#pragma unroll
  for (int i = 0; i < 4; i++)
    dst[(size_t)(threadIdx.y + i * 8) * HID + threadIdx.x] = f2bf(tile[threadIdx.x][threadIdx.y + i * 8]);
}

// ---------------- GEMM1: h = relu(xb[tok] @ W1t^T + b1), 128x128 tile, BK=64 ----------------
__global__ __launch_bounds__(256)
void k_gemm1(const unsigned short* __restrict__ xb, const unsigned short* __restrict__ W1t,
             const float* __restrict__ b1, const int* __restrict__ pair_token,
             const int* __restrict__ offsets_pad, unsigned short* __restrict__ h) {
  const int tid = threadIdx.x;
  const int lane = tid & 63;
  const int wv = tid >> 6;
  const int p0 = blockIdx.y * 128;
  if (p0 >= offsets_pad[NE]) return;
  const int n0 = blockIdx.x * 128;

  int e = 0;
#pragma unroll
  for (int i = 1; i < NE; i++) if (p0 >= offsets_pad[i]) e = i;

  __shared__ alignas(16) unsigned short sA[128 * 64];
  __shared__ alignas(16) unsigned short sB[128 * 64];
  __shared__ int tok[128];
  if (tid < 128) tok[tid] = pair_token[p0 + tid];

  const unsigned short* Bp = W1t + ((size_t)e * HID + n0) * DIN;

  floatx4 acc[4][4];
#pragma unroll
  for (int i = 0; i < 4; i++)
#pragma unroll
    for (int j = 0; j < 4; j++) acc[i][j] = (floatx4){0.f, 0.f, 0.f, 0.f};

  const int wm = wv >> 1, wn = wv & 1;
  const int frow = lane & 15;
  const int fk = (lane >> 4) * 8;
  const int sr = tid >> 3;   // 0..31
  const int sc = tid & 7;    // 16B chunk

  for (int k0 = 0; k0 < DIN; k0 += 64) {
    __syncthreads();
#pragma unroll
    for (int i = 0; i < 4; i++) {
      int row = i * 32 + sr;
      gload16(xb + (size_t)tok[row] * DIN + k0 + sc * 8, &sA[(i * 32 + wv * 8) * 64]);
    }
#pragma unroll
    for (int i = 0; i < 4; i++) {
      int row = i * 32 + sr;
      gload16(Bp + (size_t)row * DIN + k0 + sc * 8, &sB[(i * 32 + wv * 8) * 64]);
    }
    __syncthreads();
#pragma unroll
    for (int kk = 0; kk < 64; kk += 32) {
      short8 af[4], bfr[4];
#pragma unroll
      for (int m = 0; m < 4; m++)
        af[m] = *(const short8*)&sA[(wm * 64 + m * 16 + frow) * 64 + kk + fk];
#pragma unroll
      for (int n = 0; n < 4; n++)
        bfr[n] = *(const short8*)&sB[(wn * 64 + n * 16 + frow) * 64 + kk + fk];
#pragma unroll
      for (int m = 0; m < 4; m++)
#pragma unroll
        for (int n = 0; n < 4; n++)
          acc[m][n] = __builtin_amdgcn_mfma_f32_16x16x32_bf16(af[m], bfr[n], acc[m][n], 0, 0, 0);
    }
  }

  const int orow = (lane >> 4) * 4;
  const int ocol = lane & 15;
#pragma unroll
  for (int n = 0; n < 4; n++) {
    int col = n0 + wn * 64 + n * 16 + ocol;
    float bias = b1[e * HID + col];
#pragma unroll
    for (int m = 0; m < 4; m++) {
      int prow = p0 + wm * 64 + m * 16 + orow;
      unsigned short* hp = h + (size_t)prow * HID + col;
#pragma unroll
      for (int j = 0; j < 4; j++) {
        float v = acc[m][n][j] + bias;
        hp[(size_t)j * HID] = f2bf(fmaxf(v, 0.f));
      }
    }
  }
}

// ---------------- GEMM2: y = h @ W2t^T + b2, 128x128 tile, BK=64 ----------------
__global__ __launch_bounds__(256)
void k_gemm2(const unsigned short* __restrict__ h, const unsigned short* __restrict__ W2t,
             const float* __restrict__ b2, const int* __restrict__ offsets_pad,
             float* __restrict__ y) {
  const int tid = threadIdx.x;
  const int lane = tid & 63;
  const int wv = tid >> 6;
  const int p0 = blockIdx.y * 128;
  if (p0 >= offsets_pad[NE]) return;
  const int n0 = blockIdx.x * 128;

  int e = 0;
#pragma unroll
  for (int i = 1; i < NE; i++) if (p0 >= offsets_pad[i]) e = i;

  __shared__ alignas(16) unsigned short sA[128 * 64];
  __shared__ alignas(16) unsigned short sB[128 * 64];

  const unsigned short* Ap = h + (size_t)p0 * HID;
  const unsigned short* Bp = W2t + ((size_t)e * CPAD + n0) * HID;

  floatx4 acc[4][4];
#pragma unroll
  for (int i = 0; i < 4; i++)
#pragma unroll
    for (int j = 0; j < 4; j++) acc[i][j] = (floatx4){0.f, 0.f, 0.f, 0.f};

  const int wm = wv >> 1, wn = wv & 1;
  const int frow = lane & 15;
  const int fk = (lane >> 4) * 8;
  const int sr = tid >> 3;
  const int sc = tid & 7;

  for (int k0 = 0; k0 < HID; k0 += 64) {
    __syncthreads();
#pragma unroll
    for (int i = 0; i < 4; i++) {
      int row = i * 32 + sr;
      gload16(Ap + (size_t)row * HID + k0 + sc * 8, &sA[(i * 32 + wv * 8) * 64]);
    }
#pragma unroll
    for (int i = 0; i < 4; i++) {
      int row = i * 32 + sr;
      gload16(Bp + (size_t)row * HID + k0 + sc * 8, &sB[(i * 32 + wv * 8) * 64]);
    }
    __syncthreads();
#pragma unroll
    for (int kk = 0; kk < 64; kk += 32) {
      short8 af[4], bfr[4];
#pragma unroll
      for (int m = 0; m < 4; m++)
        af[m] = *(const short8*)&sA[(wm * 64 + m * 16 + frow) * 64 + kk + fk];
#pragma unroll
      for (int n = 0; n < 4; n++)
        bfr[n] = *(const short8*)&sB[(wn * 64 + n * 16 + frow) * 64 + kk + fk];
#pragma unroll
      for (int m = 0; m < 4; m++)
#pragma unroll
        for (int n = 0; n < 4; n++)
          acc[m][n] = __builtin_amdgcn_mfma_f32_16x16x32_bf16(af[m], bfr[n], acc[m][n], 0, 0, 0);
    }
  }

  const int orow = (lane >> 4) * 4;
  const int ocol = lane & 15;
#pragma unroll
  for (int n = 0; n < 4; n++) {
    int col = n0 + wn * 64 + n * 16 + ocol;
    float bias = (col < CLS) ? b2[e * CLS + col] : 0.f;
#pragma unroll
    for (int m = 0; m < 4; m++) {
      int prow = p0 + wm * 64 + m * 16 + orow;
      float* yp = y + (size_t)prow * CPAD + col;
#pragma unroll
      for (int j = 0; j < 4; j++) yp[(size_t)j * CPAD] = acc[m][n][j] + bias;
    }
  }
}

// ---------------- combine: out[b,c] = w0*y[pos0,c] + w1*y[pos1,c] ----------------
__global__ void k_combine(const float* __restrict__ y, const int* __restrict__ pos_of,
                          const float* __restrict__ topk_w, float* __restrict__ out) {
  int b = blockIdx.x;
  int q0 = pos_of[b * 2], q1 = pos_of[b * 2 + 1];
  float w0 = topk_w[b * 2], w1 = topk_w[b * 2 + 1];
  const float* y0 = y + (size_t)q0 * CPAD;
  const float* y1 = y + (size_t)q1 * CPAD;
  float* o = out + (size_t)b * CLS;
  for (int c = threadIdx.x; c < CLS; c += 256) o[c] = w0 * y0[c] + w1 * y1[c];
}

__global__ void k_sentinel(float* out) { if (threadIdx.x == 0) out[0] = 1.0e9f; }

extern "C" void kernel_launch(void* const* d_in, const int* in_sizes, int n_in,
                              void* d_out, int out_size, void* d_ws, size_t ws_size,
                              hipStream_t stream) {
  const float* x  = (const float*)d_in[0];
  const float* Wg = (const float*)d_in[1];
  const float* bg = (const float*)d_in[2];
  const float* W1 = (const float*)d_in[3];
  const float* b1 = (const float*)d_in[4];
  const float* W2 = (const float*)d_in[5];
  const float* b2 = (const float*)d_in[6];
  float* out = (float*)d_out;

  char* w = (char*)d_ws;
  int* counts = (int*)w;       w += 256;
  int* offsets_pad = (int*)w;  w += 256;
  int* cursor = (int*)w;       w += 256;
  float* part = (float*)w;     w += (size_t)PART_BLOCKS * NE * 4;
  int* topk_e = (int*)w;       w += (size_t)B_TOK * 2 * 4;
  float* topk_w = (float*)w;   w += (size_t)B_TOK * 2 * 4;
  int* pos_of = (int*)w;       w += (size_t)B_TOK * 2 * 4;
  int* pair_token = (int*)w;   w += (size_t)PAIR_CAP * 4;
  unsigned short* xb = (unsigned short*)w;   w += (size_t)B_TOK * DIN * 2;
  unsigned short* W1t = (unsigned short*)w;  w += (size_t)NE * HID * DIN * 2;
  unsigned short* W2t = (unsigned short*)w;  w += (size_t)NE * CPAD * HID * 2;
  unsigned short* hbuf = (unsigned short*)w; w += (size_t)PAIR_CAP * HID * 2;
  float* ybuf = (float*)w;     w += (size_t)PAIR_CAP * CPAD * 4;
  size_t need = (size_t)(w - (char*)d_ws);
  if (ws_size < need) {
    k_sentinel<<<1, 64, 0, stream>>>(out);
    return;
  }

  hipMemsetAsync(d_ws, 0, 768, stream);

  k_gate<<<PART_BLOCKS, 256, 0, stream>>>(x, Wg, bg, counts, part, topk_e, topk_w);
  k_setup<<<1, 256, 0, stream>>>(counts, offsets_pad, cursor, part, pair_token,
                                 out + (size_t)B_TOK * CLS);
  k_scatter<<<B_TOK / 256, 256, 0, stream>>>(topk_e, cursor, pair_token, pos_of);

  k_cast_x<<<(B_TOK * DIN / 4) / 256, 256, 0, stream>>>((const float4*)x, (ushort4*)xb);
  k_trans_w1<<<dim3(HID / 32, DIN / 32, NE), dim3(32, 8), 0, stream>>>(W1, W1t);
  k_trans_w2<<<dim3(CPAD / 32, HID / 32, NE), dim3(32, 8), 0, stream>>>(W2, W2t);

  k_gemm1<<<dim3(HID / 128, PAIR_CAP / 128), 256, 0, stream>>>(xb, W1t, b1, pair_token,
                                                               offsets_pad, hbuf);
  k_gemm2<<<dim3(CPAD / 128, PAIR_CAP / 128), 256, 0, stream>>>(hbuf, W2t, b2,
                                                                offsets_pad, ybuf);
  k_combine<<<B_TOK, 256, 0, stream>>>(ybuf, pos_of, topk_w, out);
}

// Round 2
// 814.924 us; speedup vs baseline: 1.1167x; 1.1167x over previous
//
#include <hip/hip_runtime.h>
#include <hip/hip_bf16.h>
#include <cstdint>

#define B_TOK 8192
#define DIN   1024
#define HID   4096
#define CLS   1000
#define CPAD  1024
#define NE    8
#define PAIR_CAP 18432           // 16384 + 8*256, multiple of 256
#define PART_BLOCKS 2048

typedef __attribute__((ext_vector_type(8))) short short8;
typedef __attribute__((ext_vector_type(4))) float floatx4;

__device__ __forceinline__ unsigned short f2bf(float f) {
  unsigned int u = __builtin_bit_cast(unsigned int, f);
  u += 0x7fffu + ((u >> 16) & 1u);   // RNE
  return (unsigned short)(u >> 16);
}

__device__ __forceinline__ void gload16(const void* g, void* l) {
  __builtin_amdgcn_global_load_lds(
      (const __attribute__((address_space(1))) void*)(uintptr_t)g,
      (__attribute__((address_space(3))) void*)(unsigned int)(uintptr_t)l,
      16, 0, 0);
}

#define BARRIER() asm volatile("s_barrier" ::: "memory")
#define VMCNT4()  asm volatile("s_waitcnt vmcnt(4)" ::: "memory")
#define VMCNT0()  asm volatile("s_waitcnt vmcnt(0)" ::: "memory")

// swizzled LDS read: 16B at (row, byte-in-row), XOR-swizzle on 16B slot
__device__ __forceinline__ short8 ldsrd(const unsigned short* buf, int row, int bir) {
  const char* p = (const char*)buf + row * 128 + (bir ^ ((row & 7) << 4));
  return *(const short8*)p;
}

// ---------------- gating: one wave per token ----------------
__global__ void k_gate(const float* __restrict__ x, const float* __restrict__ Wg,
                       const float* __restrict__ bg, int* __restrict__ counts,
                       float* __restrict__ part, int* __restrict__ topk_e,
                       float* __restrict__ topk_w) {
  int tok = (blockIdx.x * blockDim.x + threadIdx.x) >> 6;
  int lane = threadIdx.x & 63;
  __shared__ float psum[NE];
  if (threadIdx.x < NE) psum[threadIdx.x] = 0.f;
  __syncthreads();

  float acc[NE];
#pragma unroll
  for (int e = 0; e < NE; e++) acc[e] = 0.f;
  const float* xr = x + (size_t)tok * DIN;
  for (int d = lane; d < DIN; d += 64) {
    float xv = xr[d];
    const float* wr = Wg + d * NE;
#pragma unroll
    for (int e = 0; e < NE; e++) acc[e] += xv * wr[e];
  }
#pragma unroll
  for (int e = 0; e < NE; e++)
    for (int off = 32; off; off >>= 1) acc[e] += __shfl_xor(acc[e], off);

  if (lane == 0) {
    float p[NE];
    float m = -1e30f;
#pragma unroll
    for (int e = 0; e < NE; e++) { p[e] = acc[e] + bg[e]; m = fmaxf(m, p[e]); }
    float s = 0.f;
#pragma unroll
    for (int e = 0; e < NE; e++) { p[e] = expf(p[e] - m); s += p[e]; }
    float inv = 1.f / s;
#pragma unroll
    for (int e = 0; e < NE; e++) p[e] *= inv;
    int e0 = 0;
#pragma unroll
    for (int e = 1; e < NE; e++) if (p[e] > p[e0]) e0 = e;
    int e1 = -1;
#pragma unroll
    for (int e = 0; e < NE; e++) {
      if (e == e0) continue;
      if (e1 < 0 || p[e] > p[e1]) e1 = e;
    }
    float wi = 1.f / (p[e0] + p[e1]);
    topk_e[tok * 2] = e0;  topk_e[tok * 2 + 1] = e1;
    topk_w[tok * 2] = p[e0] * wi;  topk_w[tok * 2 + 1] = p[e1] * wi;
    atomicAdd(&counts[e0], 1);
    atomicAdd(&counts[e1], 1);
#pragma unroll
    for (int e = 0; e < NE; e++) atomicAdd(&psum[e], p[e]);
  }
  __syncthreads();
  if (threadIdx.x < NE) part[blockIdx.x * NE + threadIdx.x] = psum[threadIdx.x];
}

// ---------------- setup: offsets (256-pad), cursors, lb_loss, dummy fill ----------------
__global__ void k_setup(const int* __restrict__ counts, int* __restrict__ offsets_pad,
                        int* __restrict__ cursor, const float* __restrict__ part,
                        int* __restrict__ pair_token, float* __restrict__ out_lb) {
  __shared__ int soff[NE + 1];
  __shared__ float ssum[NE];
  int t = threadIdx.x;
  float loc[NE];
#pragma unroll
  for (int e = 0; e < NE; e++) loc[e] = 0.f;
  for (int i = t; i < PART_BLOCKS; i += blockDim.x)
#pragma unroll
    for (int e = 0; e < NE; e++) loc[e] += part[i * NE + e];
  if (t < NE) ssum[t] = 0.f;
  __syncthreads();
#pragma unroll
  for (int e = 0; e < NE; e++) atomicAdd(&ssum[e], loc[e]);
  __syncthreads();
  if (t == 0) {
    float lb = 0.f;
    for (int e = 0; e < NE; e++) {
      float mean = ssum[e] / (float)B_TOK;
      lb += mean * mean;
    }
    *out_lb = lb * (float)NE;
    int off = 0;
    for (int e = 0; e < NE; e++) {
      soff[e] = off;
      off += ((counts[e] + 255) >> 8) << 8;
    }
    soff[NE] = off;
  }
  __syncthreads();
  if (t <= NE) offsets_pad[t] = soff[t];
  if (t < NE) cursor[t] = soff[t];
  for (int e = 0; e < NE; e++) {
    int s0 = soff[e] + counts[e], s1 = soff[e + 1];
    for (int i = s0 + t; i < s1; i += blockDim.x) pair_token[i] = 0;
  }
}

// ---------------- scatter tokens into expert buckets ----------------
__global__ void k_scatter(const int* __restrict__ topk_e, int* __restrict__ cursor,
                          int* __restrict__ pair_token, int* __restrict__ pos_of) {
  int b = blockIdx.x * blockDim.x + threadIdx.x;
  if (b >= B_TOK) return;
#pragma unroll
  for (int k = 0; k < 2; k++) {
    int e = topk_e[b * 2 + k];
    int pos = atomicAdd(&cursor[e], 1);
    pair_token[pos] = b;
    pos_of[b * 2 + k] = pos;
  }
}

// ---------------- cast x to bf16 ----------------
__global__ void k_cast_x(const float4* __restrict__ x4, ushort4* __restrict__ xb4) {
  int i = blockIdx.x * blockDim.x + threadIdx.x;
  float4 v = x4[i];
  ushort4 o;
  o.x = f2bf(v.x); o.y = f2bf(v.y); o.z = f2bf(v.z); o.w = f2bf(v.w);
  xb4[i] = o;
}

// ---------------- transpose+cast W1: [E][DIN][HID] f32 -> [E][HID][DIN] bf16 ----------------
__global__ void k_trans_w1(const float* __restrict__ W1, unsigned short* __restrict__ W1t) {
  __shared__ float tile[32][33];
  int e = blockIdx.z;
  int n0 = blockIdx.x * 32;
  int k0 = blockIdx.y * 32;
  const float* src = W1 + ((size_t)e * DIN + k0) * HID + n0;
#pragma unroll
  for (int i = 0; i < 4; i++)
    tile[threadIdx.y + i * 8][threadIdx.x] = src[(size_t)(threadIdx.y + i * 8) * HID + threadIdx.x];
  __syncthreads();
  unsigned short* dst = W1t + ((size_t)e * HID + n0) * DIN + k0;
#pragma unroll
  for (int i = 0; i < 4; i++)
    dst[(size_t)(threadIdx.y + i * 8) * DIN + threadIdx.x] = f2bf(tile[threadIdx.x][threadIdx.y + i * 8]);
}

// ---------------- transpose+cast W2: [E][HID][CLS] f32 -> [E][CPAD][HID] bf16 ----------------
__global__ void k_trans_w2(const float* __restrict__ W2, unsigned short* __restrict__ W2t) {
  __shared__ float tile[32][33];
  int e = blockIdx.z;
  int n0 = blockIdx.x * 32;
  int k0 = blockIdx.y * 32;
#pragma unroll
  for (int i = 0; i < 4; i++) {
    int n = n0 + threadIdx.x;
    float v = 0.f;
    if (n < CLS) v = W2[((size_t)e * HID + k0 + threadIdx.y + i * 8) * CLS + n];
    tile[threadIdx.y + i * 8][threadIdx.x] = v;
  }
  __syncthreads();
  unsigned short* dst = W2t + ((size_t)e * CPAD + n0) * HID + k0;
#pragma unroll
  for (int i = 0; i < 4; i++)
    dst[(size_t)(threadIdx.y + i * 8) * HID + threadIdx.x] = f2bf(tile[threadIdx.x][threadIdx.y + i * 8]);
}

// ================= 256x256 multi-phase grouped GEMM =================
// BM=BN=256, BK=64, 8 waves (2Mx4N), 512 threads, 128KiB dbuf LDS,
// per-K-tile 4 phases, counted vmcnt(4) once per K-tile at P4.
// LDS swizzle: byte-in-row ^= ((row&7)<<4); applied via pre-swizzled
// global source (gload_lds writes linearly) + swizzled ds_read.
template<int NT, int A_ROW_BYTES, int B_ROW_BYTES, bool GATHER, bool OUT_BF16_RELU,
         int BIAS_STRIDE, int OUT_STRIDE, int NCOLS_VALID>
__global__ __launch_bounds__(512, 2)
void k_gemm256(const unsigned short* __restrict__ Amat,
               const unsigned short* __restrict__ Bmat,
               const float* __restrict__ bias,
               const int* __restrict__ pair_token,
               const int* __restrict__ offsets_pad,
               void* __restrict__ outp,
               size_t b_expert_stride) {
  const int tid = threadIdx.x;
  const int lane = tid & 63;
  const int w = tid >> 6;            // wave 0..7
  const int wm = w >> 2;             // 0..1
  const int wn = w & 3;              // 0..3
  const int p0 = blockIdx.y * 256;
  if (p0 >= offsets_pad[NE]) return;
  const int n0 = blockIdx.x * 256;

  int e = 0;
#pragma unroll
  for (int i = 1; i < NE; i++) if (p0 >= offsets_pad[i]) e = i;

  __shared__ alignas(16) unsigned short sA[2 * 256 * 64];   // 64 KiB
  __shared__ alignas(16) unsigned short sB[2 * 256 * 64];   // 64 KiB

  const int rl = lane >> 3;                 // 0..7
  const int swz16 = ((lane & 7) ^ rl) << 4; // pre-swizzled 16B slot
  const int frow = lane & 15;
  const int fkb = (lane >> 4) << 4;         // byte offset of k-chunk

  // per-thread staging source addresses: [half][i]
  const char* asrc[2][2];
  const char* bsrc[2][2];
  const char* Bexp = (const char*)(Bmat + (size_t)e * b_expert_stride);
#pragma unroll
  for (int h = 0; h < 2; h++)
#pragma unroll
    for (int i = 0; i < 2; i++) {
      int r = h * 128 + w * 16 + i * 8 + rl;
      if constexpr (GATHER) {
        int tk = pair_token[p0 + r];
        asrc[h][i] = (const char*)Amat + (size_t)tk * A_ROW_BYTES + swz16;
      } else {
        asrc[h][i] = (const char*)Amat + (size_t)(p0 + r) * A_ROW_BYTES + swz16;
      }
      bsrc[h][i] = Bexp + (size_t)(n0 + r) * B_ROW_BYTES + swz16;
    }

  floatx4 acc[8][4];
#pragma unroll
  for (int i = 0; i < 8; i++)
#pragma unroll
    for (int j = 0; j < 4; j++) acc[i][j] = (floatx4){0.f, 0.f, 0.f, 0.f};

  // staging macros: LDS dest is wave-uniform; lane offset is implicit (+lane*16)
#define STAGE_A(h, dst, koff)                                            \
  gload16(asrc[h][0] + (koff), (dst) + ((h) * 128 + w * 16 + 0) * 64);   \
  gload16(asrc[h][1] + (koff), (dst) + ((h) * 128 + w * 16 + 8) * 64);
#define STAGE_B(h, dst, koff)                                            \
  gload16(bsrc[h][0] + (koff), (dst) + ((h) * 128 + w * 16 + 0) * 64);   \
  gload16(bsrc[h][1] + (koff), (dst) + ((h) * 128 + w * 16 + 8) * 64);

  // prologue: tile0 A+B -> buf0 (8 loads), tile1 A -> buf1 (4 loads), vmcnt(4)
  STAGE_A(0, sA, 0); STAGE_A(1, sA, 0);
  STAGE_B(0, sB, 0); STAGE_B(1, sB, 0);
  STAGE_A(0, sA + 16384, 128); STAGE_A(1, sA + 16384, 128);
  VMCNT4();
  BARRIER();

#define RD_A(mh)                                                              \
  _Pragma("unroll") for (int mi = 0; mi < 4; mi++)                            \
  _Pragma("unroll") for (int kk = 0; kk < 2; kk++)                            \
    a[mi][kk] = ldsrd(pA, wm * 128 + (mh) * 64 + mi * 16 + frow, kk * 64 + fkb);
#define RD_B(nh)                                                              \
  _Pragma("unroll") for (int ni = 0; ni < 2; ni++)                            \
  _Pragma("unroll") for (int kk = 0; kk < 2; kk++)                            \
    b[ni][kk] = ldsrd(pB, wn * 64 + (nh) * 32 + ni * 16 + frow, kk * 64 + fkb);
#define MFMA_Q(mh, nh)                                                        \
  __builtin_amdgcn_s_setprio(1);                                              \
  _Pragma("unroll") for (int mi = 0; mi < 4; mi++)                            \
  _Pragma("unroll") for (int ni = 0; ni < 2; ni++)                            \
  _Pragma("unroll") for (int kk = 0; kk < 2; kk++)                            \
    acc[(mh) * 4 + mi][(nh) * 2 + ni] = __builtin_amdgcn_mfma_f32_16x16x32_bf16( \
        a[mi][kk], b[ni][kk], acc[(mh) * 4 + mi][(nh) * 2 + ni], 0, 0, 0);    \
  __builtin_amdgcn_s_setprio(0);

  for (int t = 0; t < NT; ++t) {
    const int cur = t & 1;
    unsigned short* pA = sA + cur * 16384;
    unsigned short* pB = sB + cur * 16384;
    unsigned short* qB = sB + (cur ^ 1) * 16384;
    const bool s1 = (t + 1 < NT);
    const bool s2 = (t + 2 < NT);
    const size_t off1 = (size_t)(t + 1) * 128;
    const size_t off2 = (size_t)(t + 2) * 128;

    short8 a[4][2];
    short8 b[2][2];

    // P1: read A-m0 (8) + B-n0 (4); stage B-half0(t+1)
    RD_A(0); RD_B(0);
    if (s1) { STAGE_B(0, qB, off1); }
    BARRIER();
    MFMA_Q(0, 0);
    BARRIER();

    // P2: read B-n1 (4); stage B-half1(t+1)
    RD_B(1);
    if (s1) { STAGE_B(1, qB, off1); }
    BARRIER();
    MFMA_Q(0, 1);
    BARRIER();

    // P3: read A-m1 (8); no stage
    RD_A(1);
    BARRIER();
    MFMA_Q(1, 1);
    BARRIER();

    // P4: re-read B-n0 (4); stage A halves(t+2) into current A buffer
    // (A(t) regions dead after P3's barrier); counted vmcnt once per K-tile.
    RD_B(0);
    if (s2) { STAGE_A(0, pA, off2); STAGE_A(1, pA, off2); }
    if (s2) { VMCNT4(); } else { VMCNT0(); }
    BARRIER();
    MFMA_Q(1, 0);
    BARRIER();
  }
#undef RD_A
#undef RD_B
#undef MFMA_Q
#undef STAGE_A
#undef STAGE_B

  // epilogue
  const int cl = lane & 15;
  const int rj = (lane >> 4) * 4;
  const int ocol0 = n0 + wn * 64;
  const int orow0 = p0 + wm * 128;
  if constexpr (OUT_BF16_RELU) {
    unsigned short* out = (unsigned short*)outp;
#pragma unroll
    for (int ni = 0; ni < 4; ni++) {
      int col = ocol0 + ni * 16 + cl;
      float bv = bias[e * BIAS_STRIDE + col];
#pragma unroll
      for (int mi = 0; mi < 8; mi++) {
        size_t rbase = (size_t)(orow0 + mi * 16 + rj) * OUT_STRIDE + col;
#pragma unroll
        for (int j = 0; j < 4; j++) {
          float v = acc[mi][ni][j] + bv;
          out[rbase + (size_t)j * OUT_STRIDE] = f2bf(fmaxf(v, 0.f));
        }
      }
    }
  } else {
    float* out = (float*)outp;
#pragma unroll
    for (int ni = 0; ni < 4; ni++) {
      int col = ocol0 + ni * 16 + cl;
      float bv = (col < NCOLS_VALID) ? bias[e * BIAS_STRIDE + col] : 0.f;
#pragma unroll
      for (int mi = 0; mi < 8; mi++) {
        size_t rbase = (size_t)(orow0 + mi * 16 + rj) * OUT_STRIDE + col;
#pragma unroll
        for (int j = 0; j < 4; j++) out[rbase + (size_t)j * OUT_STRIDE] = acc[mi][ni][j] + bv;
      }
    }
  }
}

// ---------------- combine ----------------
__global__ void k_combine(const float* __restrict__ y, const int* __restrict__ pos_of,
                          const float* __restrict__ topk_w, float* __restrict__ out) {
  int b = blockIdx.x;
  int q0 = pos_of[b * 2], q1 = pos_of[b * 2 + 1];
  float w0 = topk_w[b * 2], w1 = topk_w[b * 2 + 1];
  const float* y0 = y + (size_t)q0 * CPAD;
  const float* y1 = y + (size_t)q1 * CPAD;
  float* o = out + (size_t)b * CLS;
  for (int c = threadIdx.x; c < CLS; c += 256) o[c] = w0 * y0[c] + w1 * y1[c];
}

__global__ void k_sentinel(float* out) { if (threadIdx.x == 0) out[0] = 1.0e9f; }

extern "C" void kernel_launch(void* const* d_in, const int* in_sizes, int n_in,
                              void* d_out, int out_size, void* d_ws, size_t ws_size,
                              hipStream_t stream) {
  const float* x  = (const float*)d_in[0];
  const float* Wg = (const float*)d_in[1];
  const float* bg = (const float*)d_in[2];
  const float* W1 = (const float*)d_in[3];
  const float* b1 = (const float*)d_in[4];
  const float* W2 = (const float*)d_in[5];
  const float* b2 = (const float*)d_in[6];
  float* out = (float*)d_out;

  char* w = (char*)d_ws;
  int* counts = (int*)w;       w += 256;
  int* offsets_pad = (int*)w;  w += 256;
  int* cursor = (int*)w;       w += 256;
  float* part = (float*)w;     w += (size_t)PART_BLOCKS * NE * 4;
  int* topk_e = (int*)w;       w += (size_t)B_TOK * 2 * 4;
  float* topk_w = (float*)w;   w += (size_t)B_TOK * 2 * 4;
  int* pos_of = (int*)w;       w += (size_t)B_TOK * 2 * 4;
  int* pair_token = (int*)w;   w += (size_t)PAIR_CAP * 4;
  // big region; ybuf aliases xb+W1t (both dead before GEMM2 writes y)
  char* big = w;
  unsigned short* xb = (unsigned short*)big;
  unsigned short* W1t = (unsigned short*)(big + (size_t)B_TOK * DIN * 2);
  unsigned short* W2t = (unsigned short*)(big + (size_t)B_TOK * DIN * 2 + (size_t)NE * HID * DIN * 2);
  unsigned short* hbuf = (unsigned short*)((char*)W2t + (size_t)NE * CPAD * HID * 2);
  float* ybuf = (float*)big;   // needs PAIR_CAP*CPAD*4 = 75.5MB <= xb+W1t = 83.9MB
  size_t need = (size_t)(((char*)hbuf + (size_t)PAIR_CAP * HID * 2) - (char*)d_ws);
  if (ws_size < need) {
    k_sentinel<<<1, 64, 0, stream>>>(out);
    return;
  }

  hipMemsetAsync(d_ws, 0, 768, stream);

  k_gate<<<PART_BLOCKS, 256, 0, stream>>>(x, Wg, bg, counts, part, topk_e, topk_w);
  k_setup<<<1, 256, 0, stream>>>(counts, offsets_pad, cursor, part, pair_token,
                                 out + (size_t)B_TOK * CLS);
  k_scatter<<<B_TOK / 256, 256, 0, stream>>>(topk_e, cursor, pair_token, pos_of);

  k_cast_x<<<(B_TOK * DIN / 4) / 256, 256, 0, stream>>>((const float4*)x, (ushort4*)xb);
  k_trans_w1<<<dim3(HID / 32, DIN / 32, NE), dim3(32, 8), 0, stream>>>(W1, W1t);
  k_trans_w2<<<dim3(CPAD / 32, HID / 32, NE), dim3(32, 8), 0, stream>>>(W2, W2t);

  // GEMM1: h = relu(xb[gather] @ W1t^T + b1)   M=PAIR_CAP N=HID K=DIN
  k_gemm256<DIN / 64, DIN * 2, DIN * 2, true, true, HID, HID, HID>
      <<<dim3(HID / 256, PAIR_CAP / 256), 512, 0, stream>>>(
          xb, W1t, b1, pair_token, offsets_pad, hbuf, (size_t)HID * DIN);

  // GEMM2: y = hbuf @ W2t^T + b2               M=PAIR_CAP N=CPAD K=HID
  k_gemm256<HID / 64, HID * 2, HID * 2, false, false, CLS, CPAD, CLS>
      <<<dim3(CPAD / 256, PAIR_CAP / 256), 512, 0, stream>>>(
          hbuf, W2t, b2, pair_token, offsets_pad, ybuf, (size_t)CPAD * HID);

  k_combine<<<B_TOK, 256, 0, stream>>>(ybuf, pos_of, topk_w, out);
}

// Round 4
// 810.543 us; speedup vs baseline: 1.1227x; 1.0054x over previous
//
#include <hip/hip_runtime.h>
#include <hip/hip_bf16.h>
#include <cstdint>

#define B_TOK 8192
#define DIN   1024
#define HID   4096
#define CLS   1000
#define CPAD  1024
#define NE    8
#define PAIR_CAP 18432           // 16384 + 8*256, multiple of 256
#define PART_BLOCKS 2048

typedef __attribute__((ext_vector_type(8))) short short8;
typedef __attribute__((ext_vector_type(4))) float floatx4;

__device__ __forceinline__ unsigned short f2bf(float f) {
  unsigned int u = __builtin_bit_cast(unsigned int, f);
  u += 0x7fffu + ((u >> 16) & 1u);   // RNE
  return (unsigned short)(u >> 16);
}

__device__ __forceinline__ void gload16(const void* g, void* l) {
  __builtin_amdgcn_global_load_lds(
      (const __attribute__((address_space(1))) void*)(uintptr_t)g,
      (__attribute__((address_space(3))) void*)(unsigned int)(uintptr_t)l,
      16, 0, 0);
}

#define BARRIER() asm volatile("s_barrier" ::: "memory")
#define VMCNT8()  asm volatile("s_waitcnt vmcnt(8)" ::: "memory")
#define VMCNT0()  asm volatile("s_waitcnt vmcnt(0)" ::: "memory")

// swizzled LDS read: 16B at (row, byte-in-row), XOR-swizzle on 16B slot
__device__ __forceinline__ short8 ldsrd(const unsigned short* buf, int row, int bir) {
  const char* p = (const char*)buf + row * 128 + (bir ^ ((row & 7) << 4));
  return *(const short8*)p;
}

// ---------------- gating: one wave per token ----------------
__global__ void k_gate(const float* __restrict__ x, const float* __restrict__ Wg,
                       const float* __restrict__ bg, int* __restrict__ counts,
                       float* __restrict__ part, int* __restrict__ topk_e,
                       float* __restrict__ topk_w) {
  int tok = (blockIdx.x * blockDim.x + threadIdx.x) >> 6;
  int lane = threadIdx.x & 63;
  __shared__ float psum[NE];
  if (threadIdx.x < NE) psum[threadIdx.x] = 0.f;
  __syncthreads();

  float acc[NE];
#pragma unroll
  for (int e = 0; e < NE; e++) acc[e] = 0.f;
  const float* xr = x + (size_t)tok * DIN;
  for (int d = lane; d < DIN; d += 64) {
    float xv = xr[d];
    const float4* wr4 = (const float4*)(Wg + d * NE);
    float4 wa = wr4[0], wb = wr4[1];
    acc[0] += xv * wa.x; acc[1] += xv * wa.y; acc[2] += xv * wa.z; acc[3] += xv * wa.w;
    acc[4] += xv * wb.x; acc[5] += xv * wb.y; acc[6] += xv * wb.z; acc[7] += xv * wb.w;
  }
#pragma unroll
  for (int e = 0; e < NE; e++)
    for (int off = 32; off; off >>= 1) acc[e] += __shfl_xor(acc[e], off);

  if (lane == 0) {
    float p[NE];
    float m = -1e30f;
#pragma unroll
    for (int e = 0; e < NE; e++) { p[e] = acc[e] + bg[e]; m = fmaxf(m, p[e]); }
    float s = 0.f;
#pragma unroll
    for (int e = 0; e < NE; e++) { p[e] = expf(p[e] - m); s += p[e]; }
    float inv = 1.f / s;
#pragma unroll
    for (int e = 0; e < NE; e++) p[e] *= inv;
    int e0 = 0;
#pragma unroll
    for (int e = 1; e < NE; e++) if (p[e] > p[e0]) e0 = e;
    int e1 = -1;
#pragma unroll
    for (int e = 0; e < NE; e++) {
      if (e == e0) continue;
      if (e1 < 0 || p[e] > p[e1]) e1 = e;
    }
    float wi = 1.f / (p[e0] + p[e1]);
    topk_e[tok * 2] = e0;  topk_e[tok * 2 + 1] = e1;
    topk_w[tok * 2] = p[e0] * wi;  topk_w[tok * 2 + 1] = p[e1] * wi;
    atomicAdd(&counts[e0], 1);
    atomicAdd(&counts[e1], 1);
#pragma unroll
    for (int e = 0; e < NE; e++) atomicAdd(&psum[e], p[e]);
  }
  __syncthreads();
  if (threadIdx.x < NE) part[blockIdx.x * NE + threadIdx.x] = psum[threadIdx.x];
}

// ---------------- setup: offsets (256-pad), cursors, lb_loss, dummy fill ----------------
__global__ void k_setup(const int* __restrict__ counts, int* __restrict__ offsets_pad,
                        int* __restrict__ cursor, const float* __restrict__ part,
                        int* __restrict__ pair_token, float* __restrict__ out_lb) {
  __shared__ int soff[NE + 1];
  __shared__ float ssum[NE];
  int t = threadIdx.x;
  float loc[NE];
#pragma unroll
  for (int e = 0; e < NE; e++) loc[e] = 0.f;
  for (int i = t; i < PART_BLOCKS; i += blockDim.x)
#pragma unroll
    for (int e = 0; e < NE; e++) loc[e] += part[i * NE + e];
  if (t < NE) ssum[t] = 0.f;
  __syncthreads();
#pragma unroll
  for (int e = 0; e < NE; e++) atomicAdd(&ssum[e], loc[e]);
  __syncthreads();
  if (t == 0) {
    float lb = 0.f;
    for (int e = 0; e < NE; e++) {
      float mean = ssum[e] / (float)B_TOK;
      lb += mean * mean;
    }
    *out_lb = lb * (float)NE;
    int off = 0;
    for (int e = 0; e < NE; e++) {
      soff[e] = off;
      off += ((counts[e] + 255) >> 8) << 8;
    }
    soff[NE] = off;
  }
  __syncthreads();
  if (t <= NE) offsets_pad[t] = soff[t];
  if (t < NE) cursor[t] = soff[t];
  for (int e = 0; e < NE; e++) {
    int s0 = soff[e] + counts[e], s1 = soff[e + 1];
    for (int i = s0 + t; i < s1; i += blockDim.x) pair_token[i] = 0;
  }
}

// ---------------- scatter tokens into expert buckets ----------------
__global__ void k_scatter(const int* __restrict__ topk_e, int* __restrict__ cursor,
                          int* __restrict__ pair_token, int* __restrict__ pos_of) {
  int b = blockIdx.x * blockDim.x + threadIdx.x;
  if (b >= B_TOK) return;
#pragma unroll
  for (int k = 0; k < 2; k++) {
    int e = topk_e[b * 2 + k];
    int pos = atomicAdd(&cursor[e], 1);
    pair_token[pos] = b;
    pos_of[b * 2 + k] = pos;
  }
}

// ---------------- cast x to bf16 ----------------
__global__ void k_cast_x(const float4* __restrict__ x4, ushort4* __restrict__ xb4) {
  int i = blockIdx.x * blockDim.x + threadIdx.x;
  float4 v = x4[i];
  ushort4 o;
  o.x = f2bf(v.x); o.y = f2bf(v.y); o.z = f2bf(v.z); o.w = f2bf(v.w);
  xb4[i] = o;
}

// ---------------- transpose+cast W1: [E][DIN][HID] f32 -> [E][HID][DIN] bf16 ----------------
__global__ void k_trans_w1(const float* __restrict__ W1, unsigned short* __restrict__ W1t) {
  __shared__ float tile[64][65];
  int e = blockIdx.z, n0 = blockIdx.x * 64, k0 = blockIdx.y * 64;
  int t = threadIdx.x;
  int rn = t & 63, rk = t >> 6;
  const float* src = W1 + ((size_t)e * DIN + k0) * HID + n0;
#pragma unroll
  for (int p = 0; p < 16; p++)
    tile[rk + p * 4][rn] = src[(size_t)(rk + p * 4) * HID + rn];
  __syncthreads();
  int wk = (t & 31) * 2, wn = t >> 5;
  unsigned short* dst = W1t + ((size_t)e * HID + n0) * DIN + k0;
#pragma unroll
  for (int p = 0; p < 8; p++) {
    int n = wn + p * 8;
    ushort2 v;
    v.x = f2bf(tile[wk][n]);
    v.y = f2bf(tile[wk + 1][n]);
    *(ushort2*)&dst[(size_t)n * DIN + wk] = v;
  }
}

// ---------------- transpose+cast W2: [E][HID][CLS] f32 -> [E][CPAD][HID] bf16 ----------------
__global__ void k_trans_w2(const float* __restrict__ W2, unsigned short* __restrict__ W2t) {
  __shared__ float tile[64][65];
  int e = blockIdx.z, n0 = blockIdx.x * 64, k0 = blockIdx.y * 64;
  int t = threadIdx.x;
  int rn = t & 63, rk = t >> 6;
#pragma unroll
  for (int p = 0; p < 16; p++) {
    int n = n0 + rn;
    float v = 0.f;
    if (n < CLS) v = W2[((size_t)e * HID + k0 + rk + p * 4) * CLS + n];
    tile[rk + p * 4][rn] = v;
  }
  __syncthreads();
  int wk = (t & 31) * 2, wn = t >> 5;
  unsigned short* dst = W2t + ((size_t)e * CPAD + n0) * HID + k0;
#pragma unroll
  for (int p = 0; p < 8; p++) {
    int n = wn + p * 8;
    ushort2 v;
    v.x = f2bf(tile[wk][n]);
    v.y = f2bf(tile[wk + 1][n]);
    *(ushort2*)&dst[(size_t)n * HID + wk] = v;
  }
}

// ================= 256x256 multi-phase grouped GEMM =================
// BM=BN=256, BK=64, 8 waves (2Mx4N), 512 threads, 128KiB dbuf LDS.
// Per K-tile 4 phases, quadrants (0,0),(0,1),(1,1),(1,0); b0 kept in regs.
// Stage B(t+2) at ph3, A(t+2) at ph4; single vmcnt(8) per K-tile ->
// waited loads were issued a full K-tile earlier (latency covered).
// KSPLIT=2: ks=0 writes outp, ks=1 writes outp2 (separate buffers!).
template<int NT, int A_ROW_BYTES, int B_ROW_BYTES, bool GATHER, bool OUT_BF16_RELU,
         int BIAS_STRIDE, int OUT_STRIDE, int NCOLS_VALID, int KSPLIT>
__global__ __launch_bounds__(512, 2)
void k_gemm256(const unsigned short* __restrict__ Amat,
               const unsigned short* __restrict__ Bmat,
               const float* __restrict__ bias,
               const int* __restrict__ pair_token,
               const int* __restrict__ offsets_pad,
               void* __restrict__ outp,
               void* __restrict__ outp2,
               size_t b_expert_stride) {
  const int tid = threadIdx.x;
  const int lane = tid & 63;
  const int w = tid >> 6;            // wave 0..7
  const int wm = w >> 2;             // 0..1
  const int wn = w & 3;              // 0..3
  const int p0 = blockIdx.y * 256;
  if (p0 >= offsets_pad[NE]) return;

  int bx = blockIdx.x, ks = 0;
  if constexpr (KSPLIT == 2) { ks = bx & 1; bx >>= 1; }
  const int n0 = bx * 256;
  const size_t kb = (size_t)ks * NT * 128;   // byte offset into a row

  int e = 0;
#pragma unroll
  for (int i = 1; i < NE; i++) if (p0 >= offsets_pad[i]) e = i;

  __shared__ alignas(16) unsigned short sA[2 * 256 * 64];   // 64 KiB
  __shared__ alignas(16) unsigned short sB[2 * 256 * 64];   // 64 KiB

  const int rl = lane >> 3;                 // 0..7
  const int swz16 = ((lane & 7) ^ rl) << 4; // pre-swizzled 16B slot
  const int frow = lane & 15;
  const int fkb = (lane >> 4) << 4;         // byte offset of k-chunk

  const char* asrc[2][2];
  const char* bsrc[2][2];
  const char* Bexp = (const char*)(Bmat + (size_t)e * b_expert_stride);
#pragma unroll
  for (int h = 0; h < 2; h++)
#pragma unroll
    for (int i = 0; i < 2; i++) {
      int r = h * 128 + w * 16 + i * 8 + rl;
      if constexpr (GATHER) {
        int tk = pair_token[p0 + r];
        asrc[h][i] = (const char*)Amat + (size_t)tk * A_ROW_BYTES + swz16;
      } else {
        asrc[h][i] = (const char*)Amat + (size_t)(p0 + r) * A_ROW_BYTES + swz16;
      }
      bsrc[h][i] = Bexp + (size_t)(n0 + r) * B_ROW_BYTES + swz16;
    }

  floatx4 acc[8][4];
#pragma unroll
  for (int i = 0; i < 8; i++)
#pragma unroll
    for (int j = 0; j < 4; j++) acc[i][j] = (floatx4){0.f, 0.f, 0.f, 0.f};

#define STAGE_A(h, dst, koff)                                            \
  gload16(asrc[h][0] + (koff), (dst) + ((h) * 128 + w * 16 + 0) * 64);   \
  gload16(asrc[h][1] + (koff), (dst) + ((h) * 128 + w * 16 + 8) * 64);
#define STAGE_B(h, dst, koff)                                            \
  gload16(bsrc[h][0] + (koff), (dst) + ((h) * 128 + w * 16 + 0) * 64);   \
  gload16(bsrc[h][1] + (koff), (dst) + ((h) * 128 + w * 16 + 8) * 64);

  // prologue: B(0),A(0) -> buf0; B(1),A(1) -> buf1; wait oldest 8 (tile0)
  STAGE_B(0, sB, kb); STAGE_B(1, sB, kb);
  STAGE_A(0, sA, kb); STAGE_A(1, sA, kb);
  STAGE_B(0, sB + 16384, kb + 128); STAGE_B(1, sB + 16384, kb + 128);
  STAGE_A(0, sA + 16384, kb + 128); STAGE_A(1, sA + 16384, kb + 128);
  VMCNT8();
  BARRIER();

#define RD_A(dst, mh)                                                         \
  _Pragma("unroll") for (int mi = 0; mi < 4; mi++)                            \
  _Pragma("unroll") for (int kk = 0; kk < 2; kk++)                            \
    dst[mi][kk] = ldsrd(pA, wm * 128 + (mh) * 64 + mi * 16 + frow, kk * 64 + fkb);
#define RD_B(dst, nh)                                                         \
  _Pragma("unroll") for (int ni = 0; ni < 2; ni++)                            \
  _Pragma("unroll") for (int kk = 0; kk < 2; kk++)                            \
    dst[ni][kk] = ldsrd(pB, wn * 64 + (nh) * 32 + ni * 16 + frow, kk * 64 + fkb);
#define MFMA_Q(fa, fb, mh, nh)                                                \
  __builtin_amdgcn_s_setprio(1);                                              \
  _Pragma("unroll") for (int mi = 0; mi < 4; mi++)                            \
  _Pragma("unroll") for (int ni = 0; ni < 2; ni++)                            \
  _Pragma("unroll") for (int kk = 0; kk < 2; kk++)                            \
    acc[(mh) * 4 + mi][(nh) * 2 + ni] = __builtin_amdgcn_mfma_f32_16x16x32_bf16( \
        fa[mi][kk], fb[ni][kk], acc[(mh) * 4 + mi][(nh) * 2 + ni], 0, 0, 0);  \
  __builtin_amdgcn_s_setprio(0);

  for (int t = 0; t < NT; ++t) {
    const int cur = t & 1;
    unsigned short* pA = sA + cur * 16384;
    unsigned short* pB = sB + cur * 16384;
    const bool s2 = (t + 2 < NT);
    const size_t off2 = kb + (size_t)(t + 2) * 128;

    short8 a[4][2], b0[2][2], b1[2][2];

    // ph1: RD a0(8) + b0(4)
    RD_A(a, 0); RD_B(b0, 0);
    BARRIER();
    MFMA_Q(a, b0, 0, 0);
    BARRIER();

    // ph2: RD b1(4)
    RD_B(b1, 1);
    BARRIER();
    MFMA_Q(a, b1, 0, 1);
    BARRIER();

    // ph3: RD a1(8) (a0 dead); stage B(t+2) into cur B-region (dead after ph2)
    RD_A(a, 1);
    if (s2) { STAGE_B(0, pB, off2); STAGE_B(1, pB, off2); }
    BARRIER();
    MFMA_Q(a, b1, 1, 1);
    BARRIER();

    // ph4: stage A(t+2) into cur A-region (dead after ph3); counted wait:
    // drains B(t+1),A(t+1) (issued one K-tile ago), leaves t+2 in flight.
    if (s2) { STAGE_A(0, pA, off2); STAGE_A(1, pA, off2); VMCNT8(); }
    else    { VMCNT0(); }
    BARRIER();
    MFMA_Q(a, b0, 1, 0);
    BARRIER();
  }
#undef RD_A
#undef RD_B
#undef MFMA_Q
#undef STAGE_A
#undef STAGE_B

  // epilogue
  const int cl = lane & 15;
  const int rj = (lane >> 4) * 4;
  const int ocol0 = n0 + wn * 64;
  const int orow0 = p0 + wm * 128;
  if constexpr (OUT_BF16_RELU) {
    unsigned short* out = (unsigned short*)outp;
#pragma unroll
    for (int ni = 0; ni < 4; ni++) {
      int col = ocol0 + ni * 16 + cl;
      float bv = bias[e * BIAS_STRIDE + col];
#pragma unroll
      for (int mi = 0; mi < 8; mi++) {
        size_t rbase = (size_t)(orow0 + mi * 16 + rj) * OUT_STRIDE + col;
#pragma unroll
        for (int j = 0; j < 4; j++) {
          float v = acc[mi][ni][j] + bv;
          out[rbase + (size_t)j * OUT_STRIDE] = f2bf(fmaxf(v, 0.f));
        }
      }
    }
  } else {
    float* out = (float*)outp;
    if constexpr (KSPLIT == 2) { if (ks) out = (float*)outp2; }
#pragma unroll
    for (int ni = 0; ni < 4; ni++) {
      int col = ocol0 + ni * 16 + cl;
      float bv = (ks == 0 && col < NCOLS_VALID) ? bias[e * BIAS_STRIDE + col] : 0.f;
#pragma unroll
      for (int mi = 0; mi < 8; mi++) {
        size_t rbase = (size_t)(orow0 + mi * 16 + rj) * OUT_STRIDE + col;
#pragma unroll
        for (int j = 0; j < 4; j++) out[rbase + (size_t)j * OUT_STRIDE] = acc[mi][ni][j] + bv;
      }
    }
  }
}

// ---------------- combine: out[b,c] = w0*(yA[q0]+yB[q0]) + w1*(yA[q1]+yB[q1]) ----------------
__global__ void k_combine(const float* __restrict__ yA, const float* __restrict__ yB,
                          const int* __restrict__ pos_of, const float* __restrict__ topk_w,
                          float* __restrict__ out) {
  int b = blockIdx.x, t = threadIdx.x;
  if (t >= 250) return;   // 250 float4 = 1000 floats
  int q0 = pos_of[b * 2], q1 = pos_of[b * 2 + 1];
  float w0 = topk_w[b * 2], w1 = topk_w[b * 2 + 1];
  const float4* a0 = (const float4*)(yA + (size_t)q0 * CPAD);
  const float4* c0 = (const float4*)(yB + (size_t)q0 * CPAD);
  const float4* a1 = (const float4*)(yA + (size_t)q1 * CPAD);
  const float4* c1 = (const float4*)(yB + (size_t)q1 * CPAD);
  float4 v0 = a0[t], u0 = c0[t], v1 = a1[t], u1 = c1[t];
  float4 r;
  r.x = w0 * (v0.x + u0.x) + w1 * (v1.x + u1.x);
  r.y = w0 * (v0.y + u0.y) + w1 * (v1.y + u1.y);
  r.z = w0 * (v0.z + u0.z) + w1 * (v1.z + u1.z);
  r.w = w0 * (v0.w + u0.w) + w1 * (v1.w + u1.w);
  ((float4*)(out + (size_t)b * CLS))[t] = r;
}

__global__ void k_sentinel(float* out) { if (threadIdx.x == 0) out[0] = 1.0e9f; }

extern "C" void kernel_launch(void* const* d_in, const int* in_sizes, int n_in,
                              void* d_out, int out_size, void* d_ws, size_t ws_size,
                              hipStream_t stream) {
  const float* x  = (const float*)d_in[0];
  const float* Wg = (const float*)d_in[1];
  const float* bg = (const float*)d_in[2];
  const float* W1 = (const float*)d_in[3];
  const float* b1 = (const float*)d_in[4];
  const float* W2 = (const float*)d_in[5];
  const float* b2 = (const float*)d_in[6];
  float* out = (float*)d_out;

  char* w = (char*)d_ws;
  int* counts = (int*)w;       w += 256;
  int* offsets_pad = (int*)w;  w += 256;
  int* cursor = (int*)w;       w += 256;
  float* part = (float*)w;     w += (size_t)PART_BLOCKS * NE * 4;
  int* topk_e = (int*)w;       w += (size_t)B_TOK * 2 * 4;
  float* topk_w = (float*)w;   w += (size_t)B_TOK * 2 * 4;
  int* pos_of = (int*)w;       w += (size_t)B_TOK * 2 * 4;
  int* pair_token = (int*)w;   w += (size_t)PAIR_CAP * 4;
  char* big = w;
  unsigned short* xb  = (unsigned short*)big;
  unsigned short* W1t = (unsigned short*)(big + (size_t)B_TOK * DIN * 2);
  unsigned short* W2t = (unsigned short*)((char*)W1t + (size_t)NE * HID * DIN * 2);
  unsigned short* hbuf = (unsigned short*)((char*)W2t + (size_t)NE * CPAD * HID * 2);
  float* ybufB = (float*)((char*)hbuf + (size_t)PAIR_CAP * HID * 2);
  // ybufA aliases xb+W1t (75.5MB <= 80MB); both dead before GEMM2 runs.
  // ybufA never reaches W2t (starts at 80MB) or hbuf (144MB) -> no overlap
  // with GEMM2's live inputs. ks=1 partials go to the SEPARATE ybufB.
  float* ybufA = (float*)big;
  size_t need = (size_t)(((char*)ybufB + (size_t)PAIR_CAP * CPAD * 4) - (char*)d_ws);
  if (ws_size < need) {
    k_sentinel<<<1, 64, 0, stream>>>(out);
    return;
  }

  hipMemsetAsync(d_ws, 0, 768, stream);

  k_gate<<<PART_BLOCKS, 256, 0, stream>>>(x, Wg, bg, counts, part, topk_e, topk_w);
  k_setup<<<1, 256, 0, stream>>>(counts, offsets_pad, cursor, part, pair_token,
                                 out + (size_t)B_TOK * CLS);
  k_scatter<<<B_TOK / 256, 256, 0, stream>>>(topk_e, cursor, pair_token, pos_of);

  k_cast_x<<<(B_TOK * DIN / 4) / 256, 256, 0, stream>>>((const float4*)x, (ushort4*)xb);
  k_trans_w1<<<dim3(HID / 64, DIN / 64, NE), 256, 0, stream>>>(W1, W1t);
  k_trans_w2<<<dim3(CPAD / 64, HID / 64, NE), 256, 0, stream>>>(W2, W2t);

  // GEMM1: h = relu(xb[gather] @ W1t^T + b1)   M=PAIR_CAP N=HID K=DIN
  k_gemm256<DIN / 64, DIN * 2, DIN * 2, true, true, HID, HID, HID, 1>
      <<<dim3(HID / 256, PAIR_CAP / 256), 512, 0, stream>>>(
          xb, W1t, b1, pair_token, offsets_pad, hbuf, nullptr, (size_t)HID * DIN);

  // GEMM2: y = hbuf @ W2t^T + b2, K-split x2   M=PAIR_CAP N=CPAD K=HID
  k_gemm256<HID / 128, HID * 2, HID * 2, false, false, CLS, CPAD, CLS, 2>
      <<<dim3((CPAD / 256) * 2, PAIR_CAP / 256), 512, 0, stream>>>(
          hbuf, W2t, b2, pair_token, offsets_pad, ybufA, ybufB, (size_t)CPAD * HID);

  k_combine<<<B_TOK, 256, 0, stream>>>(ybufA, ybufB, pos_of, topk_w, out);
}

// Round 5
// 766.596 us; speedup vs baseline: 1.1871x; 1.0573x over previous
//
#include <hip/hip_runtime.h>
#include <hip/hip_bf16.h>
#include <cstdint>

#define B_TOK 8192
#define DIN   1024
#define HID   4096
#define CLS   1000
#define CPAD  1024
#define NE    8
#define PAIR_CAP 18432           // 16384 + 8*256, multiple of 256
#define PART_BLOCKS 2048

typedef __attribute__((ext_vector_type(8))) short short8;
typedef __attribute__((ext_vector_type(4))) float floatx4;

__device__ __forceinline__ unsigned short f2bf(float f) {
  unsigned int u = __builtin_bit_cast(unsigned int, f);
  u += 0x7fffu + ((u >> 16) & 1u);   // RNE
  return (unsigned short)(u >> 16);
}

__device__ __forceinline__ void gload16(const void* g, void* l) {
  __builtin_amdgcn_global_load_lds(
      (const __attribute__((address_space(1))) void*)(uintptr_t)g,
      (__attribute__((address_space(3))) void*)(unsigned int)(uintptr_t)l,
      16, 0, 0);
}

#define BARRIER() asm volatile("s_barrier" ::: "memory")
#define VMCNT8()  asm volatile("s_waitcnt vmcnt(8)" ::: "memory")
#define VMCNT0()  asm volatile("s_waitcnt vmcnt(0)" ::: "memory")

// swizzled LDS read: 16B at (row, byte-in-row), XOR-swizzle on 16B slot
__device__ __forceinline__ short8 ldsrd(const unsigned short* buf, int row, int bir) {
  const char* p = (const char*)buf + row * 128 + (bir ^ ((row & 7) << 4));
  return *(const short8*)p;
}

// ---------------- gating: one wave per token (fused x -> bf16 cast) ----------------
__global__ void k_gate(const float* __restrict__ x, const float* __restrict__ Wg,
                       const float* __restrict__ bg, int* __restrict__ counts,
                       float* __restrict__ part, int* __restrict__ topk_e,
                       float* __restrict__ topk_w, ushort4* __restrict__ xb4) {
  int tok = (blockIdx.x * blockDim.x + threadIdx.x) >> 6;
  int lane = threadIdx.x & 63;
  __shared__ float psum[NE];
  if (threadIdx.x < NE) psum[threadIdx.x] = 0.f;
  __syncthreads();

  float acc[NE];
#pragma unroll
  for (int e = 0; e < NE; e++) acc[e] = 0.f;
  const float4* xr4 = (const float4*)(x + (size_t)tok * DIN);
#pragma unroll
  for (int i = 0; i < 4; i++) {
    int d4 = lane + i * 64;
    float4 v = xr4[d4];
    ushort4 o;
    o.x = f2bf(v.x); o.y = f2bf(v.y); o.z = f2bf(v.z); o.w = f2bf(v.w);
    xb4[(size_t)tok * (DIN / 4) + d4] = o;
    float vs[4] = {v.x, v.y, v.z, v.w};
#pragma unroll
    for (int c = 0; c < 4; c++) {
      const float4* wr4 = (const float4*)(Wg + (size_t)(d4 * 4 + c) * NE);
      float4 wa = wr4[0], wb = wr4[1];
      float xv = vs[c];
      acc[0] += xv * wa.x; acc[1] += xv * wa.y; acc[2] += xv * wa.z; acc[3] += xv * wa.w;
      acc[4] += xv * wb.x; acc[5] += xv * wb.y; acc[6] += xv * wb.z; acc[7] += xv * wb.w;
    }
  }
#pragma unroll
  for (int e = 0; e < NE; e++)
    for (int off = 32; off; off >>= 1) acc[e] += __shfl_xor(acc[e], off);

  if (lane == 0) {
    float p[NE];
    float m = -1e30f;
#pragma unroll
    for (int e = 0; e < NE; e++) { p[e] = acc[e] + bg[e]; m = fmaxf(m, p[e]); }
    float s = 0.f;
#pragma unroll
    for (int e = 0; e < NE; e++) { p[e] = expf(p[e] - m); s += p[e]; }
    float inv = 1.f / s;
#pragma unroll
    for (int e = 0; e < NE; e++) p[e] *= inv;
    int e0 = 0;
#pragma unroll
    for (int e = 1; e < NE; e++) if (p[e] > p[e0]) e0 = e;
    int e1 = -1;
#pragma unroll
    for (int e = 0; e < NE; e++) {
      if (e == e0) continue;
      if (e1 < 0 || p[e] > p[e1]) e1 = e;
    }
    float wi = 1.f / (p[e0] + p[e1]);
    topk_e[tok * 2] = e0;  topk_e[tok * 2 + 1] = e1;
    topk_w[tok * 2] = p[e0] * wi;  topk_w[tok * 2 + 1] = p[e1] * wi;
    atomicAdd(&counts[e0], 1);
    atomicAdd(&counts[e1], 1);
#pragma unroll
    for (int e = 0; e < NE; e++) atomicAdd(&psum[e], p[e]);
  }
  __syncthreads();
  if (threadIdx.x < NE) part[blockIdx.x * NE + threadIdx.x] = psum[threadIdx.x];
}

// ---------------- setup: offsets (256-pad), cursors, lb_loss, dummy fill ----------------
__global__ void k_setup(const int* __restrict__ counts, int* __restrict__ offsets_pad,
                        int* __restrict__ cursor, const float* __restrict__ part,
                        int* __restrict__ pair_token, float* __restrict__ out_lb) {
  __shared__ int soff[NE + 1];
  __shared__ float ssum[NE];
  int t = threadIdx.x;
  float loc[NE];
#pragma unroll
  for (int e = 0; e < NE; e++) loc[e] = 0.f;
  for (int i = t; i < PART_BLOCKS; i += blockDim.x)
#pragma unroll
    for (int e = 0; e < NE; e++) loc[e] += part[i * NE + e];
  if (t < NE) ssum[t] = 0.f;
  __syncthreads();
#pragma unroll
  for (int e = 0; e < NE; e++) atomicAdd(&ssum[e], loc[e]);
  __syncthreads();
  if (t == 0) {
    float lb = 0.f;
    for (int e = 0; e < NE; e++) {
      float mean = ssum[e] / (float)B_TOK;
      lb += mean * mean;
    }
    *out_lb = lb * (float)NE;
    int off = 0;
    for (int e = 0; e < NE; e++) {
      soff[e] = off;
      off += ((counts[e] + 255) >> 8) << 8;
    }
    soff[NE] = off;
  }
  __syncthreads();
  if (t <= NE) offsets_pad[t] = soff[t];
  if (t < NE) cursor[t] = soff[t];
  for (int e = 0; e < NE; e++) {
    int s0 = soff[e] + counts[e], s1 = soff[e + 1];
    for (int i = s0 + t; i < s1; i += blockDim.x) pair_token[i] = 0;
  }
}

// ---------------- scatter tokens into expert buckets ----------------
__global__ void k_scatter(const int* __restrict__ topk_e, int* __restrict__ cursor,
                          int* __restrict__ pair_token, int* __restrict__ pos_of) {
  int b = blockIdx.x * blockDim.x + threadIdx.x;
  if (b >= B_TOK) return;
#pragma unroll
  for (int k = 0; k < 2; k++) {
    int e = topk_e[b * 2 + k];
    int pos = atomicAdd(&cursor[e], 1);
    pair_token[pos] = b;
    pos_of[b * 2 + k] = pos;
  }
}

// ---------------- transpose+cast W1: [E][DIN][HID] f32 -> [E][HID][DIN] bf16 ----------------
// 64x64 tile, 256 threads; float4 loads, ushort4 stores (128B-contig runs).
__global__ void k_trans_w1(const float* __restrict__ W1, unsigned short* __restrict__ W1t) {
  __shared__ float tile[64][65];
  int e = blockIdx.z, n0 = blockIdx.x * 64, k0 = blockIdx.y * 64;
  int t = threadIdx.x;
  int r = t >> 4, c4 = (t & 15) * 4;
  const float* src = W1 + ((size_t)e * DIN + k0) * HID + n0;
#pragma unroll
  for (int p = 0; p < 4; p++) {
    int k = r + p * 16;
    float4 v = *(const float4*)&src[(size_t)k * HID + c4];
    tile[k][c4] = v.x; tile[k][c4 + 1] = v.y; tile[k][c4 + 2] = v.z; tile[k][c4 + 3] = v.w;
  }
  __syncthreads();
  int wk = (t & 15) * 4, n = t >> 4;
  unsigned short* dst = W1t + ((size_t)e * HID + n0) * DIN + k0;
#pragma unroll
  for (int p = 0; p < 4; p++) {
    int nn = n + p * 16;
    ushort4 o;
    o.x = f2bf(tile[wk][nn]);     o.y = f2bf(tile[wk + 1][nn]);
    o.z = f2bf(tile[wk + 2][nn]); o.w = f2bf(tile[wk + 3][nn]);
    *(ushort4*)&dst[(size_t)nn * DIN + wk] = o;
  }
}

// ---------------- transpose+cast W2: [E][HID][CLS] f32 -> [E][CPAD][HID] bf16 ----------------
__global__ void k_trans_w2(const float* __restrict__ W2, unsigned short* __restrict__ W2t) {
  __shared__ float tile[64][65];
  int e = blockIdx.z, n0 = blockIdx.x * 64, k0 = blockIdx.y * 64;
  int t = threadIdx.x;
  int r = t >> 4, c4 = (t & 15) * 4;
  const float* src = W2 + ((size_t)e * HID + k0) * CLS + n0;
  if (n0 + 64 <= CLS) {
#pragma unroll
    for (int p = 0; p < 4; p++) {
      int k = r + p * 16;
      float4 v = *(const float4*)&src[(size_t)k * CLS + c4];
      tile[k][c4] = v.x; tile[k][c4 + 1] = v.y; tile[k][c4 + 2] = v.z; tile[k][c4 + 3] = v.w;
    }
  } else {
#pragma unroll
    for (int p = 0; p < 4; p++) {
      int k = r + p * 16;
#pragma unroll
      for (int c = 0; c < 4; c++) {
        int n = n0 + c4 + c;
        tile[k][c4 + c] = (n < CLS) ? src[(size_t)k * CLS + c4 + c] : 0.f;
      }
    }
  }
  __syncthreads();
  int wk = (t & 15) * 4, n = t >> 4;
  unsigned short* dst = W2t + ((size_t)e * CPAD + n0) * HID + k0;
#pragma unroll
  for (int p = 0; p < 4; p++) {
    int nn = n + p * 16;
    ushort4 o;
    o.x = f2bf(tile[wk][nn]);     o.y = f2bf(tile[wk + 1][nn]);
    o.z = f2bf(tile[wk + 2][nn]); o.w = f2bf(tile[wk + 3][nn]);
    *(ushort4*)&dst[(size_t)nn * HID + wk] = o;
  }
}

// ================= 256x256 multi-phase grouped GEMM =================
// BM=BN=256, BK=64, 8 waves (2Mx4N), 512 threads, 128KiB dbuf LDS.
// Minimal-barrier schedule: 3 barriers/K-tile (only the LDS-hazard-bearing
// ones); waves skew so ds_read overlaps MFMA across waves. Counted vmcnt(8)
// once per K-tile, after ph4's MFMA, before the tile-end barrier.
// KSPLIT=2: ks=0 -> outp, ks=1 -> outp2. XCD-bijective blockIdx swizzle.
template<int NT, int A_ROW_BYTES, int B_ROW_BYTES, bool GATHER, bool OUT_BF16_RELU,
         int BIAS_STRIDE, int OUT_STRIDE, int NCOLS_VALID, int KSPLIT>
__global__ __launch_bounds__(512, 2)
void k_gemm256(const unsigned short* __restrict__ Amat,
               const unsigned short* __restrict__ Bmat,
               const float* __restrict__ bias,
               const int* __restrict__ pair_token,
               const int* __restrict__ offsets_pad,
               void* __restrict__ outp,
               void* __restrict__ outp2,
               size_t b_expert_stride) {
  const int tid = threadIdx.x;
  const int lane = tid & 63;
  const int w = tid >> 6;            // wave 0..7
  const int wm = w >> 2;             // 0..1
  const int wn = w & 3;              // 0..3

  // XCD-bijective swizzle (nwg % 8 == 0 for all our grids)
  const int nwg = gridDim.x * gridDim.y;
  const int orig = blockIdx.y * gridDim.x + blockIdx.x;
  const int wg = (orig & 7) * (nwg >> 3) + (orig >> 3);
  int bx = wg % gridDim.x;
  const int by = wg / gridDim.x;

  const int p0 = by * 256;
  if (p0 >= offsets_pad[NE]) return;

  int ks = 0;
  if constexpr (KSPLIT == 2) { ks = bx & 1; bx >>= 1; }
  const int n0 = bx * 256;
  const size_t kb = (size_t)ks * NT * 128;   // byte offset into a row

  int e = 0;
#pragma unroll
  for (int i = 1; i < NE; i++) if (p0 >= offsets_pad[i]) e = i;

  __shared__ alignas(16) unsigned short sA[2 * 256 * 64];   // 64 KiB
  __shared__ alignas(16) unsigned short sB[2 * 256 * 64];   // 64 KiB

  const int rl = lane >> 3;                 // 0..7
  const int swz16 = ((lane & 7) ^ rl) << 4; // pre-swizzled 16B slot
  const int frow = lane & 15;
  const int fkb = (lane >> 4) << 4;         // byte offset of k-chunk

  const char* asrc[2][2];
  const char* bsrc[2][2];
  const char* Bexp = (const char*)(Bmat + (size_t)e * b_expert_stride);
#pragma unroll
  for (int h = 0; h < 2; h++)
#pragma unroll
    for (int i = 0; i < 2; i++) {
      int r = h * 128 + w * 16 + i * 8 + rl;
      if constexpr (GATHER) {
        int tk = pair_token[p0 + r];
        asrc[h][i] = (const char*)Amat + (size_t)tk * A_ROW_BYTES + swz16;
      } else {
        asrc[h][i] = (const char*)Amat + (size_t)(p0 + r) * A_ROW_BYTES + swz16;
      }
      bsrc[h][i] = Bexp + (size_t)(n0 + r) * B_ROW_BYTES + swz16;
    }

  floatx4 acc[8][4];
#pragma unroll
  for (int i = 0; i < 8; i++)
#pragma unroll
    for (int j = 0; j < 4; j++) acc[i][j] = (floatx4){0.f, 0.f, 0.f, 0.f};

#define STAGE_A(h, dst, koff)                                            \
  gload16(asrc[h][0] + (koff), (dst) + ((h) * 128 + w * 16 + 0) * 64);   \
  gload16(asrc[h][1] + (koff), (dst) + ((h) * 128 + w * 16 + 8) * 64);
#define STAGE_B(h, dst, koff)                                            \
  gload16(bsrc[h][0] + (koff), (dst) + ((h) * 128 + w * 16 + 0) * 64);   \
  gload16(bsrc[h][1] + (koff), (dst) + ((h) * 128 + w * 16 + 8) * 64);

  // prologue: B(0),A(0) -> buf0; B(1),A(1) -> buf1; wait oldest 8 (tile0)
  STAGE_B(0, sB, kb); STAGE_B(1, sB, kb);
  STAGE_A(0, sA, kb); STAGE_A(1, sA, kb);
  STAGE_B(0, sB + 16384, kb + 128); STAGE_B(1, sB + 16384, kb + 128);
  STAGE_A(0, sA + 16384, kb + 128); STAGE_A(1, sA + 16384, kb + 128);
  VMCNT8();
  BARRIER();

#define RD_A(dst, mh)                                                         \
  _Pragma("unroll") for (int mi = 0; mi < 4; mi++)                            \
  _Pragma("unroll") for (int kk = 0; kk < 2; kk++)                            \
    dst[mi][kk] = ldsrd(pA, wm * 128 + (mh) * 64 + mi * 16 + frow, kk * 64 + fkb);
#define RD_B(dst, nh)                                                         \
  _Pragma("unroll") for (int ni = 0; ni < 2; ni++)                            \
  _Pragma("unroll") for (int kk = 0; kk < 2; kk++)                            \
    dst[ni][kk] = ldsrd(pB, wn * 64 + (nh) * 32 + ni * 16 + frow, kk * 64 + fkb);
#define MFMA_Q(fa, fb, mh, nh)                                                \
  __builtin_amdgcn_s_setprio(1);                                              \
  _Pragma("unroll") for (int mi = 0; mi < 4; mi++)                            \
  _Pragma("unroll") for (int ni = 0; ni < 2; ni++)                            \
  _Pragma("unroll") for (int kk = 0; kk < 2; kk++)                            \
    acc[(mh) * 4 + mi][(nh) * 2 + ni] = __builtin_amdgcn_mfma_f32_16x16x32_bf16( \
        fa[mi][kk], fb[ni][kk], acc[(mh) * 4 + mi][(nh) * 2 + ni], 0, 0, 0);  \
  __builtin_amdgcn_s_setprio(0);

  for (int t = 0; t < NT; ++t) {
    const int cur = t & 1;
    unsigned short* pA = sA + cur * 16384;
    unsigned short* pB = sB + cur * 16384;
    const bool s2 = (t + 2 < NT);
    const size_t off2 = kb + (size_t)(t + 2) * 128;

    short8 a[4][2], b0[2][2], b1[2][2];

    // ph1: RD a0(8) + b0(4); MFMA q(0,0).  (no barrier: stages only touch
    // the opposite buffer; read-completion forced by lgkmcnt before MFMA)
    RD_A(a, 0); RD_B(b0, 0);
    MFMA_Q(a, b0, 0, 0);

    // ph2: RD b1(4); MFMA q(0,1); BARRIER -> all waves' B(t) reads complete
    RD_B(b1, 1);
    MFMA_Q(a, b1, 0, 1);
    BARRIER();

    // ph3: RD a1(8); stage B(t+2) into cur B-region (quiesced); MFMA q(1,1);
    // BARRIER -> all waves' A(t) reads complete
    RD_A(a, 1);
    if (s2) { STAGE_B(0, pB, off2); STAGE_B(1, pB, off2); }
    MFMA_Q(a, b1, 1, 1);
    BARRIER();

    // ph4: stage A(t+2) into cur A-region (quiesced); MFMA q(1,0);
    // counted vmcnt AFTER the MFMA (only must precede tile-end barrier):
    // drains B(t+1),A(t+1), leaves t+2's 8 loads in flight.
    if (s2) { STAGE_A(0, pA, off2); STAGE_A(1, pA, off2); }
    MFMA_Q(a, b0, 1, 0);
    if (s2) { VMCNT8(); } else { VMCNT0(); }
    BARRIER();
  }
#undef RD_A
#undef RD_B
#undef MFMA_Q
#undef STAGE_A
#undef STAGE_B

  // epilogue
  const int cl = lane & 15;
  const int rj = (lane >> 4) * 4;
  const int ocol0 = n0 + wn * 64;
  const int orow0 = p0 + wm * 128;
  if constexpr (OUT_BF16_RELU) {
    unsigned short* out = (unsigned short*)outp;
#pragma unroll
    for (int ni = 0; ni < 4; ni++) {
      int col = ocol0 + ni * 16 + cl;
      float bv = bias[e * BIAS_STRIDE + col];
#pragma unroll
      for (int mi = 0; mi < 8; mi++) {
        size_t rbase = (size_t)(orow0 + mi * 16 + rj) * OUT_STRIDE + col;
#pragma unroll
        for (int j = 0; j < 4; j++) {
          float v = acc[mi][ni][j] + bv;
          out[rbase + (size_t)j * OUT_STRIDE] = f2bf(fmaxf(v, 0.f));
        }
      }
    }
  } else {
    float* out = (float*)outp;
    if constexpr (KSPLIT == 2) { if (ks) out = (float*)outp2; }
#pragma unroll
    for (int ni = 0; ni < 4; ni++) {
      int col = ocol0 + ni * 16 + cl;
      float bv = (ks == 0 && col < NCOLS_VALID) ? bias[e * BIAS_STRIDE + col] : 0.f;
#pragma unroll
      for (int mi = 0; mi < 8; mi++) {
        size_t rbase = (size_t)(orow0 + mi * 16 + rj) * OUT_STRIDE + col;
#pragma unroll
        for (int j = 0; j < 4; j++) out[rbase + (size_t)j * OUT_STRIDE] = acc[mi][ni][j] + bv;
      }
    }
  }
}

// ---------------- combine: out[b,c] = w0*(yA[q0]+yB[q0]) + w1*(yA[q1]+yB[q1]) ----------------
__global__ void k_combine(const float* __restrict__ yA, const float* __restrict__ yB,
                          const int* __restrict__ pos_of, const float* __restrict__ topk_w,
                          float* __restrict__ out) {
  int b = blockIdx.x, t = threadIdx.x;
  if (t >= 250) return;   // 250 float4 = 1000 floats
  int q0 = pos_of[b * 2], q1 = pos_of[b * 2 + 1];
  float w0 = topk_w[b * 2], w1 = topk_w[b * 2 + 1];
  const float4* a0 = (const float4*)(yA + (size_t)q0 * CPAD);
  const float4* c0 = (const float4*)(yB + (size_t)q0 * CPAD);
  const float4* a1 = (const float4*)(yA + (size_t)q1 * CPAD);
  const float4* c1 = (const float4*)(yB + (size_t)q1 * CPAD);
  float4 v0 = a0[t], u0 = c0[t], v1 = a1[t], u1 = c1[t];
  float4 r;
  r.x = w0 * (v0.x + u0.x) + w1 * (v1.x + u1.x);
  r.y = w0 * (v0.y + u0.y) + w1 * (v1.y + u1.y);
  r.z = w0 * (v0.z + u0.z) + w1 * (v1.z + u1.z);
  r.w = w0 * (v0.w + u0.w) + w1 * (v1.w + u1.w);
  ((float4*)(out + (size_t)b * CLS))[t] = r;
}

__global__ void k_sentinel(float* out) { if (threadIdx.x == 0) out[0] = 1.0e9f; }

extern "C" void kernel_launch(void* const* d_in, const int* in_sizes, int n_in,
                              void* d_out, int out_size, void* d_ws, size_t ws_size,
                              hipStream_t stream) {
  const float* x  = (const float*)d_in[0];
  const float* Wg = (const float*)d_in[1];
  const float* bg = (const float*)d_in[2];
  const float* W1 = (const float*)d_in[3];
  const float* b1 = (const float*)d_in[4];
  const float* W2 = (const float*)d_in[5];
  const float* b2 = (const float*)d_in[6];
  float* out = (float*)d_out;

  char* w = (char*)d_ws;
  int* counts = (int*)w;       w += 256;
  int* offsets_pad = (int*)w;  w += 256;
  int* cursor = (int*)w;       w += 256;
  float* part = (float*)w;     w += (size_t)PART_BLOCKS * NE * 4;
  int* topk_e = (int*)w;       w += (size_t)B_TOK * 2 * 4;
  float* topk_w = (float*)w;   w += (size_t)B_TOK * 2 * 4;
  int* pos_of = (int*)w;       w += (size_t)B_TOK * 2 * 4;
  int* pair_token = (int*)w;   w += (size_t)PAIR_CAP * 4;
  char* big = w;
  unsigned short* xb  = (unsigned short*)big;
  unsigned short* W1t = (unsigned short*)(big + (size_t)B_TOK * DIN * 2);
  unsigned short* W2t = (unsigned short*)((char*)W1t + (size_t)NE * HID * DIN * 2);
  unsigned short* hbuf = (unsigned short*)((char*)W2t + (size_t)NE * CPAD * HID * 2);
  float* ybufB = (float*)((char*)hbuf + (size_t)PAIR_CAP * HID * 2);
  // ybufA aliases xb+W1t (75.5MB <= 80MB); both dead before GEMM2 runs.
  // ks=1 partials go to the SEPARATE ybufB region.
  float* ybufA = (float*)big;
  size_t need = (size_t)(((char*)ybufB + (size_t)PAIR_CAP * CPAD * 4) - (char*)d_ws);
  if (ws_size < need) {
    k_sentinel<<<1, 64, 0, stream>>>(out);
    return;
  }

  hipMemsetAsync(d_ws, 0, 768, stream);

  k_gate<<<PART_BLOCKS, 256, 0, stream>>>(x, Wg, bg, counts, part, topk_e, topk_w,
                                          (ushort4*)xb);
  k_setup<<<1, 256, 0, stream>>>(counts, offsets_pad, cursor, part, pair_token,
                                 out + (size_t)B_TOK * CLS);
  k_scatter<<<B_TOK / 256, 256, 0, stream>>>(topk_e, cursor, pair_token, pos_of);

  k_trans_w1<<<dim3(HID / 64, DIN / 64, NE), 256, 0, stream>>>(W1, W1t);
  k_trans_w2<<<dim3(CPAD / 64, HID / 64, NE), 256, 0, stream>>>(W2, W2t);

  // GEMM1: h = relu(xb[gather] @ W1t^T + b1)   M=PAIR_CAP N=HID K=DIN
  k_gemm256<DIN / 64, DIN * 2, DIN * 2, true, true, HID, HID, HID, 1>
      <<<dim3(HID / 256, PAIR_CAP / 256), 512, 0, stream>>>(
          xb, W1t, b1, pair_token, offsets_pad, hbuf, nullptr, (size_t)HID * DIN);

  // GEMM2: y = hbuf @ W2t^T + b2, K-split x2   M=PAIR_CAP N=CPAD K=HID
  k_gemm256<HID / 128, HID * 2, HID * 2, false, false, CLS, CPAD, CLS, 2>
      <<<dim3((CPAD / 256) * 2, PAIR_CAP / 256), 512, 0, stream>>>(
          hbuf, W2t, b2, pair_token, offsets_pad, ybufA, ybufB, (size_t)CPAD * HID);

  k_combine<<<B_TOK, 256, 0, stream>>>(ybufA, ybufB, pos_of, topk_w, out);
}

// Round 6
// 539.925 us; speedup vs baseline: 1.6854x; 1.4198x over previous
//
#include <hip/hip_runtime.h>
#include <hip/hip_bf16.h>
#include <cstdint>

#define B_TOK 8192
#define DIN   1024
#define HID   4096
#define CLS   1000
#define CPAD  1024
#define NE    8
#define PAIR_CAP 18432           // 16384 + 8*256, multiple of 256
#define PART_BLOCKS 2048

typedef __attribute__((ext_vector_type(8))) short short8;
typedef __attribute__((ext_vector_type(4))) float floatx4;

__device__ __forceinline__ unsigned short f2bf(float f) {
  unsigned int u = __builtin_bit_cast(unsigned int, f);
  u += 0x7fffu + ((u >> 16) & 1u);   // RNE
  return (unsigned short)(u >> 16);
}

__device__ __forceinline__ void gload16(const void* g, void* l) {
  __builtin_amdgcn_global_load_lds(
      (const __attribute__((address_space(1))) void*)(uintptr_t)g,
      (__attribute__((address_space(3))) void*)(unsigned int)(uintptr_t)l,
      16, 0, 0);
}

#define BARRIER() asm volatile("s_barrier" ::: "memory")
#define VMCNT8()  asm volatile("s_waitcnt vmcnt(8)" ::: "memory")
#define VMCNT0()  asm volatile("s_waitcnt vmcnt(0)" ::: "memory")
// rule #18: sched_barrier(0) after inline-asm lgkmcnt so MFMA isn't hoisted past it
#define WAIT_LDS() do { asm volatile("s_waitcnt lgkmcnt(0)" ::: "memory"); \
                        __builtin_amdgcn_sched_barrier(0); } while (0)

// swizzled LDS read: 16B at (row, byte-in-row), XOR-swizzle on 16B slot
__device__ __forceinline__ short8 ldsrd(const unsigned short* buf, int row, int bir) {
  const char* p = (const char*)buf + row * 128 + (bir ^ ((row & 7) << 4));
  return *(const short8*)p;
}

// ---------------- gating: one wave per token (fused x -> bf16 cast; NO global atomics) ----------------
__global__ void k_gate(const float* __restrict__ x, const float* __restrict__ Wg,
                       const float* __restrict__ bg,
                       float* __restrict__ part, int* __restrict__ topk_e,
                       float* __restrict__ topk_w, ushort4* __restrict__ xb4) {
  int tok = (blockIdx.x * blockDim.x + threadIdx.x) >> 6;
  int lane = threadIdx.x & 63;
  __shared__ float psum[NE];
  if (threadIdx.x < NE) psum[threadIdx.x] = 0.f;
  __syncthreads();

  float acc[NE];
#pragma unroll
  for (int e = 0; e < NE; e++) acc[e] = 0.f;
  const float4* xr4 = (const float4*)(x + (size_t)tok * DIN);
#pragma unroll
  for (int i = 0; i < 4; i++) {
    int d4 = lane + i * 64;
    float4 v = xr4[d4];
    ushort4 o;
    o.x = f2bf(v.x); o.y = f2bf(v.y); o.z = f2bf(v.z); o.w = f2bf(v.w);
    xb4[(size_t)tok * (DIN / 4) + d4] = o;
    float vs[4] = {v.x, v.y, v.z, v.w};
#pragma unroll
    for (int c = 0; c < 4; c++) {
      const float4* wr4 = (const float4*)(Wg + (size_t)(d4 * 4 + c) * NE);
      float4 wa = wr4[0], wb = wr4[1];
      float xv = vs[c];
      acc[0] += xv * wa.x; acc[1] += xv * wa.y; acc[2] += xv * wa.z; acc[3] += xv * wa.w;
      acc[4] += xv * wb.x; acc[5] += xv * wb.y; acc[6] += xv * wb.z; acc[7] += xv * wb.w;
    }
  }
#pragma unroll
  for (int e = 0; e < NE; e++)
    for (int off = 32; off; off >>= 1) acc[e] += __shfl_xor(acc[e], off);

  if (lane == 0) {
    float p[NE];
    float m = -1e30f;
#pragma unroll
    for (int e = 0; e < NE; e++) { p[e] = acc[e] + bg[e]; m = fmaxf(m, p[e]); }
    float s = 0.f;
#pragma unroll
    for (int e = 0; e < NE; e++) { p[e] = expf(p[e] - m); s += p[e]; }
    float inv = 1.f / s;
#pragma unroll
    for (int e = 0; e < NE; e++) p[e] *= inv;
    int e0 = 0;
#pragma unroll
    for (int e = 1; e < NE; e++) if (p[e] > p[e0]) e0 = e;
    int e1 = -1;
#pragma unroll
    for (int e = 0; e < NE; e++) {
      if (e == e0) continue;
      if (e1 < 0 || p[e] > p[e1]) e1 = e;
    }
    float wi = 1.f / (p[e0] + p[e1]);
    topk_e[tok * 2] = e0;  topk_e[tok * 2 + 1] = e1;
    topk_w[tok * 2] = p[e0] * wi;  topk_w[tok * 2 + 1] = p[e1] * wi;
#pragma unroll
    for (int e = 0; e < NE; e++) atomicAdd(&psum[e], p[e]);   // LDS only
  }
  __syncthreads();
  if (threadIdx.x < NE) part[blockIdx.x * NE + threadIdx.x] = psum[threadIdx.x];
}

// ---------------- setup: histogram counts, offsets (256-pad), cursors, lb_loss, dummy fill ----------------
__global__ void k_setup(const int* __restrict__ topk_e, int* __restrict__ offsets_pad,
                        int* __restrict__ cursor, const float* __restrict__ part,
                        int* __restrict__ pair_token, float* __restrict__ out_lb) {
  __shared__ int scnt[NE];
  __shared__ int soff[NE + 1];
  __shared__ float ssum[NE];
  int t = threadIdx.x;            // 1024 threads
  int lane = t & 63;
  if (t < NE) { scnt[t] = 0; ssum[t] = 0.f; }
  __syncthreads();
  // histogram of expert choices (LDS atomics only)
  for (int i = t; i < B_TOK * 2; i += 1024) atomicAdd(&scnt[topk_e[i]], 1);
  // gate-prob partial sums
  float loc[NE];
#pragma unroll
  for (int e = 0; e < NE; e++) loc[e] = 0.f;
  for (int i = t; i < PART_BLOCKS; i += 1024)
#pragma unroll
    for (int e = 0; e < NE; e++) loc[e] += part[i * NE + e];
#pragma unroll
  for (int e = 0; e < NE; e++)
    for (int off = 32; off; off >>= 1) loc[e] += __shfl_xor(loc[e], off);
  if (lane == 0)
#pragma unroll
    for (int e = 0; e < NE; e++) atomicAdd(&ssum[e], loc[e]);
  __syncthreads();
  if (t == 0) {
    float lb = 0.f;
    for (int e = 0; e < NE; e++) {
      float mean = ssum[e] / (float)B_TOK;
      lb += mean * mean;
    }
    *out_lb = lb * (float)NE;
    int off = 0;
    for (int e = 0; e < NE; e++) {
      soff[e] = off;
      off += ((scnt[e] + 255) >> 8) << 8;
    }
    soff[NE] = off;
  }
  __syncthreads();
  if (t <= NE) offsets_pad[t] = soff[t];
  if (t < NE) cursor[t] = soff[t];
  for (int e = 0; e < NE; e++) {
    int s0 = soff[e] + scnt[e], s1 = soff[e + 1];
    for (int i = s0 + t; i < s1; i += 1024) pair_token[i] = 0;
  }
}

// ---------------- scatter: hierarchical (LDS local ranks, 8 global atomics/block) ----------------
__global__ void k_scatter(const int* __restrict__ topk_e, int* __restrict__ cursor,
                          int* __restrict__ pair_token, int* __restrict__ pos_of) {
  __shared__ int lcnt[NE], lbase[NE];
  int t = threadIdx.x;
  if (t < NE) lcnt[t] = 0;
  __syncthreads();
  int b = blockIdx.x * 256 + t;
  int ea = topk_e[b * 2], eb = topk_e[b * 2 + 1];
  int ra = atomicAdd(&lcnt[ea], 1);
  int rb = atomicAdd(&lcnt[eb], 1);
  __syncthreads();
  if (t < NE) lbase[t] = atomicAdd(&cursor[t], lcnt[t]);
  __syncthreads();
  int pa = lbase[ea] + ra, pb = lbase[eb] + rb;
  pair_token[pa] = b;  pos_of[b * 2] = pa;
  pair_token[pb] = b;  pos_of[b * 2 + 1] = pb;
}

// ---------------- transpose+cast W1: [E][DIN][HID] f32 -> [E][HID][DIN] bf16 ----------------
__global__ void k_trans_w1(const float* __restrict__ W1, unsigned short* __restrict__ W1t) {
  __shared__ float tile[64][65];
  int e = blockIdx.z, n0 = blockIdx.x * 64, k0 = blockIdx.y * 64;
  int t = threadIdx.x;
  int r = t >> 4, c4 = (t & 15) * 4;
  const float* src = W1 + ((size_t)e * DIN + k0) * HID + n0;
#pragma unroll
  for (int p = 0; p < 4; p++) {
    int k = r + p * 16;
    float4 v = *(const float4*)&src[(size_t)k * HID + c4];
    tile[k][c4] = v.x; tile[k][c4 + 1] = v.y; tile[k][c4 + 2] = v.z; tile[k][c4 + 3] = v.w;
  }
  __syncthreads();
  int wk = (t & 15) * 4, n = t >> 4;
  unsigned short* dst = W1t + ((size_t)e * HID + n0) * DIN + k0;
#pragma unroll
  for (int p = 0; p < 4; p++) {
    int nn = n + p * 16;
    ushort4 o;
    o.x = f2bf(tile[wk][nn]);     o.y = f2bf(tile[wk + 1][nn]);
    o.z = f2bf(tile[wk + 2][nn]); o.w = f2bf(tile[wk + 3][nn]);
    *(ushort4*)&dst[(size_t)nn * DIN + wk] = o;
  }
}

// ---------------- transpose+cast W2: [E][HID][CLS] f32 -> [E][CPAD][HID] bf16 ----------------
__global__ void k_trans_w2(const float* __restrict__ W2, unsigned short* __restrict__ W2t) {
  __shared__ float tile[64][65];
  int e = blockIdx.z, n0 = blockIdx.x * 64, k0 = blockIdx.y * 64;
  int t = threadIdx.x;
  int r = t >> 4, c4 = (t & 15) * 4;
  const float* src = W2 + ((size_t)e * HID + k0) * CLS + n0;
  if (n0 + 64 <= CLS) {
#pragma unroll
    for (int p = 0; p < 4; p++) {
      int k = r + p * 16;
      float4 v = *(const float4*)&src[(size_t)k * CLS + c4];
      tile[k][c4] = v.x; tile[k][c4 + 1] = v.y; tile[k][c4 + 2] = v.z; tile[k][c4 + 3] = v.w;
    }
  } else {
#pragma unroll
    for (int p = 0; p < 4; p++) {
      int k = r + p * 16;
#pragma unroll
      for (int c = 0; c < 4; c++) {
        int n = n0 + c4 + c;
        tile[k][c4 + c] = (n < CLS) ? src[(size_t)k * CLS + c4 + c] : 0.f;
      }
    }
  }
  __syncthreads();
  int wk = (t & 15) * 4, n = t >> 4;
  unsigned short* dst = W2t + ((size_t)e * CPAD + n0) * HID + k0;
#pragma unroll
  for (int p = 0; p < 4; p++) {
    int nn = n + p * 16;
    ushort4 o;
    o.x = f2bf(tile[wk][nn]);     o.y = f2bf(tile[wk + 1][nn]);
    o.z = f2bf(tile[wk + 2][nn]); o.w = f2bf(tile[wk + 3][nn]);
    *(ushort4*)&dst[(size_t)nn * HID + wk] = o;
  }
}

// ================= 256x256 multi-phase grouped GEMM =================
// BM=BN=256, BK=64, 8 waves (2Mx4N), 512 threads, 128KiB dbuf LDS.
// m201-faithful phases: {ds_reads (+stage) -> barrier -> lgkmcnt(0)+sched_barrier
// -> setprio(1) MFMA setprio(0) -> barrier}; quadrants (0,0),(0,1),(1,1),(1,0)
// with b0 in regs (ph4 has no reads). Stage B(t+2)@ph3, A(t+2)@ph4; single
// counted vmcnt(8)/K-tile after ph4's MFMA. XCD-bijective swizzle; KSPLIT=2
// writes ks=0->outp, ks=1->outp2.
template<int NT, int A_ROW_BYTES, int B_ROW_BYTES, bool GATHER, bool OUT_BF16_RELU,
         int BIAS_STRIDE, int OUT_STRIDE, int NCOLS_VALID, int KSPLIT>
__global__ __launch_bounds__(512, 2)
void k_gemm256(const unsigned short* __restrict__ Amat,
               const unsigned short* __restrict__ Bmat,
               const float* __restrict__ bias,
               const int* __restrict__ pair_token,
               const int* __restrict__ offsets_pad,
               void* __restrict__ outp,
               void* __restrict__ outp2,
               size_t b_expert_stride) {
  const int tid = threadIdx.x;
  const int lane = tid & 63;
  const int w = tid >> 6;            // wave 0..7
  const int wm = w >> 2;             // 0..1
  const int wn = w & 3;              // 0..3

  const int nwg = gridDim.x * gridDim.y;
  const int orig = blockIdx.y * gridDim.x + blockIdx.x;
  const int wg = (orig & 7) * (nwg >> 3) + (orig >> 3);
  int bx = wg % gridDim.x;
  const int by = wg / gridDim.x;

  const int p0 = by * 256;
  if (p0 >= offsets_pad[NE]) return;

  int ks = 0;
  if constexpr (KSPLIT == 2) { ks = bx & 1; bx >>= 1; }
  const int n0 = bx * 256;
  const size_t kb = (size_t)ks * NT * 128;   // byte offset into a row

  int e = 0;
#pragma unroll
  for (int i = 1; i < NE; i++) if (p0 >= offsets_pad[i]) e = i;

  __shared__ alignas(16) unsigned short sA[2 * 256 * 64];   // 64 KiB
  __shared__ alignas(16) unsigned short sB[2 * 256 * 64];   // 64 KiB

  const int rl = lane >> 3;                 // 0..7
  const int swz16 = ((lane & 7) ^ rl) << 4; // pre-swizzled 16B slot
  const int frow = lane & 15;
  const int fkb = (lane >> 4) << 4;         // byte offset of k-chunk

  const char* asrc[2][2];
  const char* bsrc[2][2];
  const char* Bexp = (const char*)(Bmat + (size_t)e * b_expert_stride);
#pragma unroll
  for (int h = 0; h < 2; h++)
#pragma unroll
    for (int i = 0; i < 2; i++) {
      int r = h * 128 + w * 16 + i * 8 + rl;
      if constexpr (GATHER) {
        int tk = pair_token[p0 + r];
        asrc[h][i] = (const char*)Amat + (size_t)tk * A_ROW_BYTES + swz16;
      } else {
        asrc[h][i] = (const char*)Amat + (size_t)(p0 + r) * A_ROW_BYTES + swz16;
      }
      bsrc[h][i] = Bexp + (size_t)(n0 + r) * B_ROW_BYTES + swz16;
    }

  floatx4 acc[8][4];
#pragma unroll
  for (int i = 0; i < 8; i++)
#pragma unroll
    for (int j = 0; j < 4; j++) acc[i][j] = (floatx4){0.f, 0.f, 0.f, 0.f};

#define STAGE_A(h, dst, koff)                                            \
  gload16(asrc[h][0] + (koff), (dst) + ((h) * 128 + w * 16 + 0) * 64);   \
  gload16(asrc[h][1] + (koff), (dst) + ((h) * 128 + w * 16 + 8) * 64);
#define STAGE_B(h, dst, koff)                                            \
  gload16(bsrc[h][0] + (koff), (dst) + ((h) * 128 + w * 16 + 0) * 64);   \
  gload16(bsrc[h][1] + (koff), (dst) + ((h) * 128 + w * 16 + 8) * 64);

  // prologue: B(0),A(0) -> buf0; B(1),A(1) -> buf1; wait oldest 8 (tile0)
  STAGE_B(0, sB, kb); STAGE_B(1, sB, kb);
  STAGE_A(0, sA, kb); STAGE_A(1, sA, kb);
  STAGE_B(0, sB + 16384, kb + 128); STAGE_B(1, sB + 16384, kb + 128);
  STAGE_A(0, sA + 16384, kb + 128); STAGE_A(1, sA + 16384, kb + 128);
  VMCNT8();
  BARRIER();

#define RD_A(dst, mh)                                                         \
  _Pragma("unroll") for (int mi = 0; mi < 4; mi++)                            \
  _Pragma("unroll") for (int kk = 0; kk < 2; kk++)                            \
    dst[mi][kk] = ldsrd(pA, wm * 128 + (mh) * 64 + mi * 16 + frow, kk * 64 + fkb);
#define RD_B(dst, nh)                                                         \
  _Pragma("unroll") for (int ni = 0; ni < 2; ni++)                            \
  _Pragma("unroll") for (int kk = 0; kk < 2; kk++)                            \
    dst[ni][kk] = ldsrd(pB, wn * 64 + (nh) * 32 + ni * 16 + frow, kk * 64 + fkb);
#define MFMA_Q(fa, fb, mh, nh)                                                \
  __builtin_amdgcn_s_setprio(1);                                              \
  _Pragma("unroll") for (int mi = 0; mi < 4; mi++)                            \
  _Pragma("unroll") for (int ni = 0; ni < 2; ni++)                            \
  _Pragma("unroll") for (int kk = 0; kk < 2; kk++)                            \
    acc[(mh) * 4 + mi][(nh) * 2 + ni] = __builtin_amdgcn_mfma_f32_16x16x32_bf16( \
        fa[mi][kk], fb[ni][kk], acc[(mh) * 4 + mi][(nh) * 2 + ni], 0, 0, 0);  \
  __builtin_amdgcn_s_setprio(0);

  for (int t = 0; t < NT; ++t) {
    const int cur = t & 1;
    unsigned short* pA = sA + cur * 16384;
    unsigned short* pB = sB + cur * 16384;
    const bool s2 = (t + 2 < NT);
    const size_t off2 = kb + (size_t)(t + 2) * 128;

    short8 a[4][2], b0[2][2], b1[2][2];

    // ph1: reads a0(8)+b0(4); batch-barrier; MFMA q(0,0)
    RD_A(a, 0); RD_B(b0, 0);
    BARRIER(); WAIT_LDS();
    MFMA_Q(a, b0, 0, 0);
    BARRIER();

    // ph2: reads b1(4); MFMA q(0,1)
    RD_B(b1, 1);
    BARRIER(); WAIT_LDS();
    MFMA_Q(a, b1, 0, 1);
    BARRIER();

    // ph3: reads a1(8); stage B(t+2) into cur B-region (all b-reads done:
    // every wave passed ph2's lgkmcnt(0)+barrier); MFMA q(1,1)
    RD_A(a, 1);
    if (s2) { STAGE_B(0, pB, off2); STAGE_B(1, pB, off2); }
    BARRIER(); WAIT_LDS();
    MFMA_Q(a, b1, 1, 1);
    BARRIER();

    // ph4: no reads (b0 in regs); stage A(t+2) into cur A-region (a-reads
    // done after ph3's barrier); MFMA q(1,0); counted vmcnt drains t+1's 8,
    // leaves t+2's 8 in flight.
    if (s2) { STAGE_A(0, pA, off2); STAGE_A(1, pA, off2); }
    MFMA_Q(a, b0, 1, 0);
    if (s2) { VMCNT8(); } else { VMCNT0(); }
    BARRIER();
  }
#undef RD_A
#undef RD_B
#undef MFMA_Q
#undef STAGE_A
#undef STAGE_B

  // epilogue
  const int cl = lane & 15;
  const int rj = (lane >> 4) * 4;
  const int ocol0 = n0 + wn * 64;
  const int orow0 = p0 + wm * 128;
  if constexpr (OUT_BF16_RELU) {
    unsigned short* out = (unsigned short*)outp;
#pragma unroll
    for (int ni = 0; ni < 4; ni++) {
      int col = ocol0 + ni * 16 + cl;
      float bv = bias[e * BIAS_STRIDE + col];
#pragma unroll
      for (int mi = 0; mi < 8; mi++) {
        size_t rbase = (size_t)(orow0 + mi * 16 + rj) * OUT_STRIDE + col;
#pragma unroll
        for (int j = 0; j < 4; j++) {
          float v = acc[mi][ni][j] + bv;
          out[rbase + (size_t)j * OUT_STRIDE] = f2bf(fmaxf(v, 0.f));
        }
      }
    }
  } else {
    float* out = (float*)outp;
    if constexpr (KSPLIT == 2) { if (ks) out = (float*)outp2; }
#pragma unroll
    for (int ni = 0; ni < 4; ni++) {
      int col = ocol0 + ni * 16 + cl;
      float bv = (ks == 0 && col < NCOLS_VALID) ? bias[e * BIAS_STRIDE + col] : 0.f;
#pragma unroll
      for (int mi = 0; mi < 8; mi++) {
        size_t rbase = (size_t)(orow0 + mi * 16 + rj) * OUT_STRIDE + col;
#pragma unroll
        for (int j = 0; j < 4; j++) out[rbase + (size_t)j * OUT_STRIDE] = acc[mi][ni][j] + bv;
      }
    }
  }
}

// ---------------- combine: out[b,c] = w0*(yA[q0]+yB[q0]) + w1*(yA[q1]+yB[q1]) ----------------
__global__ void k_combine(const float* __restrict__ yA, const float* __restrict__ yB,
                          const int* __restrict__ pos_of, const float* __restrict__ topk_w,
                          float* __restrict__ out) {
  int b = blockIdx.x, t = threadIdx.x;
  if (t >= 250) return;   // 250 float4 = 1000 floats
  int q0 = pos_of[b * 2], q1 = pos_of[b * 2 + 1];
  float w0 = topk_w[b * 2], w1 = topk_w[b * 2 + 1];
  const float4* a0 = (const float4*)(yA + (size_t)q0 * CPAD);
  const float4* c0 = (const float4*)(yB + (size_t)q0 * CPAD);
  const float4* a1 = (const float4*)(yA + (size_t)q1 * CPAD);
  const float4* c1 = (const float4*)(yB + (size_t)q1 * CPAD);
  float4 v0 = a0[t], u0 = c0[t], v1 = a1[t], u1 = c1[t];
  float4 r;
  r.x = w0 * (v0.x + u0.x) + w1 * (v1.x + u1.x);
  r.y = w0 * (v0.y + u0.y) + w1 * (v1.y + u1.y);
  r.z = w0 * (v0.z + u0.z) + w1 * (v1.z + u1.z);
  r.w = w0 * (v0.w + u0.w) + w1 * (v1.w + u1.w);
  ((float4*)(out + (size_t)b * CLS))[t] = r;
}

__global__ void k_sentinel(float* out) { if (threadIdx.x == 0) out[0] = 1.0e9f; }

extern "C" void kernel_launch(void* const* d_in, const int* in_sizes, int n_in,
                              void* d_out, int out_size, void* d_ws, size_t ws_size,
                              hipStream_t stream) {
  const float* x  = (const float*)d_in[0];
  const float* Wg = (const float*)d_in[1];
  const float* bg = (const float*)d_in[2];
  const float* W1 = (const float*)d_in[3];
  const float* b1 = (const float*)d_in[4];
  const float* W2 = (const float*)d_in[5];
  const float* b2 = (const float*)d_in[6];
  float* out = (float*)d_out;

  char* w = (char*)d_ws;
  int* offsets_pad = (int*)w;  w += 256;
  int* cursor = (int*)w;       w += 256;
  float* part = (float*)w;     w += (size_t)PART_BLOCKS * NE * 4;
  int* topk_e = (int*)w;       w += (size_t)B_TOK * 2 * 4;
  float* topk_w = (float*)w;   w += (size_t)B_TOK * 2 * 4;
  int* pos_of = (int*)w;       w += (size_t)B_TOK * 2 * 4;
  int* pair_token = (int*)w;   w += (size_t)PAIR_CAP * 4;
  char* big = w;
  unsigned short* xb  = (unsigned short*)big;
  unsigned short* W1t = (unsigned short*)(big + (size_t)B_TOK * DIN * 2);
  unsigned short* W2t = (unsigned short*)((char*)W1t + (size_t)NE * HID * DIN * 2);
  unsigned short* hbuf = (unsigned short*)((char*)W2t + (size_t)NE * CPAD * HID * 2);
  float* ybufB = (float*)((char*)hbuf + (size_t)PAIR_CAP * HID * 2);
  // ybufA aliases xb+W1t (75.5MB <= 80MB); both dead before GEMM2 runs.
  // ks=1 partials go to the SEPARATE ybufB region.
  float* ybufA = (float*)big;
  size_t need = (size_t)(((char*)ybufB + (size_t)PAIR_CAP * CPAD * 4) - (char*)d_ws);
  if (ws_size < need) {
    k_sentinel<<<1, 64, 0, stream>>>(out);
    return;
  }

  k_gate<<<PART_BLOCKS, 256, 0, stream>>>(x, Wg, bg, part, topk_e, topk_w,
                                          (ushort4*)xb);
  k_setup<<<1, 1024, 0, stream>>>(topk_e, offsets_pad, cursor, part, pair_token,
                                  out + (size_t)B_TOK * CLS);
  k_scatter<<<B_TOK / 256, 256, 0, stream>>>(topk_e, cursor, pair_token, pos_of);

  k_trans_w1<<<dim3(HID / 64, DIN / 64, NE), 256, 0, stream>>>(W1, W1t);
  k_trans_w2<<<dim3(CPAD / 64, HID / 64, NE), 256, 0, stream>>>(W2, W2t);

  // GEMM1: h = relu(xb[gather] @ W1t^T + b1)   M=PAIR_CAP N=HID K=DIN
  k_gemm256<DIN / 64, DIN * 2, DIN * 2, true, true, HID, HID, HID, 1>
      <<<dim3(HID / 256, PAIR_CAP / 256), 512, 0, stream>>>(
          xb, W1t, b1, pair_token, offsets_pad, hbuf, nullptr, (size_t)HID * DIN);

  // GEMM2: y = hbuf @ W2t^T + b2, K-split x2   M=PAIR_CAP N=CPAD K=HID
  k_gemm256<HID / 128, HID * 2, HID * 2, false, false, CLS, CPAD, CLS, 2>
      <<<dim3((CPAD / 256) * 2, PAIR_CAP / 256), 512, 0, stream>>>(
          hbuf, W2t, b2, pair_token, offsets_pad, ybufA, ybufB, (size_t)CPAD * HID);

  k_combine<<<B_TOK, 256, 0, stream>>>(ybufA, ybufB, pos_of, topk_w, out);
}